// Round 11
// baseline (1511.947 us; speedup 1.0000x reference)
//
#include <hip/hip_runtime.h>

#define DIM 128
#define HEADS 4
#define ODIM 32
#define LRELU 0.2f

typedef unsigned int u32;

// ---------------------------------------------------------------------------
// 1) H = X @ W (fp32, row-major as written). 16 rows/block, k-tiled, 36KB LDS.
// ---------------------------------------------------------------------------
__global__ __launch_bounds__(256) void proj_kernel(
    const float* __restrict__ X, const float* __restrict__ W,
    float* __restrict__ H, int n)
{
    __shared__ alignas(16) float sW[64 * DIM];   // 32 KB
    __shared__ alignas(16) float sX[16][64];     // 4 KB
    const int t = threadIdx.x;
    const int row0 = blockIdx.x * 16;
    const int c0 = (t & 31) * 4;
    const int r0 = (t >> 5) * 2;
    float a00=0,a01=0,a02=0,a03=0, a10=0,a11=0,a12=0,a13=0;

    for (int k0 = 0; k0 < DIM; k0 += 64) {
        #pragma unroll
        for (int i = 0; i < 8; ++i) {
            int idx = (i * 256 + t) * 4;
            *(float4*)&sW[idx] = *(const float4*)&W[k0 * DIM + idx];
        }
        {
            int idx = t * 4;
            int r = idx >> 6, k = idx & 63;
            int gr = row0 + r;
            float4 v = {0.f, 0.f, 0.f, 0.f};
            if (gr < n) v = *(const float4*)&X[(size_t)gr * DIM + k0 + k];
            *(float4*)&sX[r][k] = v;
        }
        __syncthreads();
        #pragma unroll 8
        for (int k = 0; k < 64; ++k) {
            float x0 = sX[r0][k], x1 = sX[r0 + 1][k];
            float4 wv = *(const float4*)&sW[k * DIM + c0];
            a00 += x0*wv.x; a01 += x0*wv.y; a02 += x0*wv.z; a03 += x0*wv.w;
            a10 += x1*wv.x; a11 += x1*wv.y; a12 += x1*wv.z; a13 += x1*wv.w;
        }
        __syncthreads();
    }
    int gr0 = row0 + r0;
    if (gr0 < n) {
        float4 v = {a00,a01,a02,a03};
        *(float4*)&H[(size_t)gr0 * DIM + c0] = v;
    }
    if (gr0 + 1 < n) {
        float4 v = {a10,a11,a12,a13};
        *(float4*)&H[(size_t)(gr0 + 1) * DIM + c0] = v;
    }
}

// ---------------------------------------------------------------------------
// 2) per-node scores: Hs[n,h] = <H[n,h,:], AL[h,:]>, Ht likewise
// ---------------------------------------------------------------------------
__global__ __launch_bounds__(256) void scores_kernel(
    const float* __restrict__ H, const float* __restrict__ AL,
    const float* __restrict__ AR, float* __restrict__ Hs, float* __restrict__ Ht,
    int n)
{
    __shared__ float sAL[HEADS * ODIM], sAR[HEADS * ODIM];
    int t = threadIdx.x;
    if (t < HEADS * ODIM) { sAL[t] = AL[t]; sAR[t] = AR[t]; }
    __syncthreads();
    int idx = blockIdx.x * 256 + t;
    if (idx >= n * HEADS) return;
    int h = idx & (HEADS - 1);
    int node = idx >> 2;
    const float* hp = &H[(size_t)node * DIM + h * ODIM];
    float s = 0.f, s2 = 0.f;
    #pragma unroll
    for (int d = 0; d < ODIM; d += 4) {
        float4 v = *(const float4*)&hp[d];
        s  += v.x*sAL[h*ODIM+d] + v.y*sAL[h*ODIM+d+1] + v.z*sAL[h*ODIM+d+2] + v.w*sAL[h*ODIM+d+3];
        s2 += v.x*sAR[h*ODIM+d] + v.y*sAR[h*ODIM+d+1] + v.z*sAR[h*ODIM+d+2] + v.w*sAR[h*ODIM+d+3];
    }
    Hs[idx] = s; Ht[idx] = s2;
}

// ---------------------------------------------------------------------------
// 3) attention scatter (reference-as-written: keyed by src, gathers H[tgt]):
//    w = exp(lrelu(Hs[src,h] + Ht[tgt,h]))
//    out[src,:] += w * H[tgt,:]   (fp32 atomics, directly into d_out)
//    den[src,h] += w
// ---------------------------------------------------------------------------
__global__ __launch_bounds__(256) void edge_kernel(
    const int* __restrict__ ei, const float* __restrict__ Hs,
    const float* __restrict__ Ht, const float2* __restrict__ H2,
    float* __restrict__ out, float* __restrict__ den, int E, int n)
{
    int wave = (blockIdx.x * 256 + threadIdx.x) >> 6;
    int L = threadIdx.x & 63;
    if (wave >= E) return;
    int src = ei[wave];          // edge_index[0][e]  (block layout)
    int tgt = ei[E + wave];      // edge_index[1][e]
    src = max(0, min(src, n - 1));
    tgt = max(0, min(tgt, n - 1));
    int h = L >> 4;
    float e = Hs[src * HEADS + h] + Ht[tgt * HEADS + h];
    float lr = e > 0.f ? e : LRELU * e;
    float w = __expf(fminf(lr, 30.f));
    float2 v = H2[(size_t)tgt * 64 + L];
    atomicAdd(&out[(size_t)src * DIM + 2 * L],     w * v.x);
    atomicAdd(&out[(size_t)src * DIM + 2 * L + 1], w * v.y);
    if ((L & 15) == 0) atomicAdd(&den[src * HEADS + h], w);
}

// ---------------------------------------------------------------------------
// 4) finalize IN PLACE: out = elu(out / (den + 1e-8))  -> fp32
// ---------------------------------------------------------------------------
__global__ __launch_bounds__(256) void out_kernel(
    float* __restrict__ out, const float* __restrict__ den, int n)
{
    int idx = blockIdx.x * 256 + threadIdx.x;   // one fp32 element
    if (idx >= n * DIM) return;
    int node = idx >> 7;
    int d = idx & 127;
    int h = d >> 5;
    float inv = 1.f / (den[node * HEADS + h] + 1e-8f);
    float o = out[idx] * inv;
    o = o > 0.f ? o : (__expf(o) - 1.f);
    out[idx] = o;
}

// ---------------------------------------------------------------------------
extern "C" void kernel_launch(void* const* d_in, const int* in_sizes, int n_in,
                              void* d_out, int out_size, void* d_ws, size_t ws_size,
                              hipStream_t stream) {
    const float* X  = (const float*)d_in[0];   // fp32 (r1/r2 NaN signature)
    const int*   EI = (const int*)d_in[1];     // int32[2E] block layout (r4 crash bound, r5 detector)
    const float* W  = (const float*)d_in[2];   // fp32 row-major
    const float* AL = (const float*)d_in[3];   // fp32 [HEADS*ODIM]
    const float* AR = (const float*)d_in[4];   // fp32 [HEADS*ODIM]
    const int n = in_sizes[0] / DIM;      // 50000
    const int E = in_sizes[1] / 2;        // 1600000

    float* out = (float*)d_out;           // fp32 output per reference dtype

    char* ws = (char*)d_ws;
    size_t o = 0;
    auto alloc = [&](size_t bytes) -> void* {
        o = (o + 255) & ~(size_t)255;
        void* p = ws + o;
        o += bytes;
        return p;
    };
    float* den = (float*)alloc((size_t)n * HEADS * 4);   // 0.8 MB
    float* Hs  = (float*)alloc((size_t)n * HEADS * 4);   // 0.8 MB
    float* Ht  = (float*)alloc((size_t)n * HEADS * 4);   // 0.8 MB
    float* H   = (float*)alloc((size_t)n * DIM * 4);     // 25.6 MB  (total 28 MB)

    hipMemsetAsync(den, 0, (size_t)n * HEADS * 4, stream);
    hipMemsetAsync(out, 0, (size_t)n * DIM * 4, stream);

    proj_kernel<<<(n + 15) / 16, 256, 0, stream>>>(X, W, H, n);
    scores_kernel<<<(n * HEADS + 255) / 256, 256, 0, stream>>>(H, AL, AR, Hs, Ht, n);
    edge_kernel<<<(E + 3) / 4, 256, 0, stream>>>(
        EI, Hs, Ht, (const float2*)H, out, den, E, n);
    out_kernel<<<(n * DIM + 255) / 256, 256, 0, stream>>>(out, den, n);
}

// Round 12
// 592.991 us; speedup vs baseline: 2.5497x; 2.5497x over previous
//
#include <hip/hip_runtime.h>

#define DIM 128
#define HEADS 4
#define ODIM 32
#define LRELU 0.2f

// ---------------------------------------------------------------------------
// 1) H = X @ W (fp32, row-major). 16 rows/block, k-tiled, 36KB LDS.
// ---------------------------------------------------------------------------
__global__ __launch_bounds__(256) void proj_kernel(
    const float* __restrict__ X, const float* __restrict__ W,
    float* __restrict__ H, int n)
{
    __shared__ alignas(16) float sW[64 * DIM];   // 32 KB
    __shared__ alignas(16) float sX[16][64];     // 4 KB
    const int t = threadIdx.x;
    const int row0 = blockIdx.x * 16;
    const int c0 = (t & 31) * 4;
    const int r0 = (t >> 5) * 2;
    float a00=0,a01=0,a02=0,a03=0, a10=0,a11=0,a12=0,a13=0;

    for (int k0 = 0; k0 < DIM; k0 += 64) {
        #pragma unroll
        for (int i = 0; i < 8; ++i) {
            int idx = (i * 256 + t) * 4;
            *(float4*)&sW[idx] = *(const float4*)&W[k0 * DIM + idx];
        }
        {
            int idx = t * 4;
            int r = idx >> 6, k = idx & 63;
            int gr = row0 + r;
            float4 v = {0.f, 0.f, 0.f, 0.f};
            if (gr < n) v = *(const float4*)&X[(size_t)gr * DIM + k0 + k];
            *(float4*)&sX[r][k] = v;
        }
        __syncthreads();
        #pragma unroll 8
        for (int k = 0; k < 64; ++k) {
            float x0 = sX[r0][k], x1 = sX[r0 + 1][k];
            float4 wv = *(const float4*)&sW[k * DIM + c0];
            a00 += x0*wv.x; a01 += x0*wv.y; a02 += x0*wv.z; a03 += x0*wv.w;
            a10 += x1*wv.x; a11 += x1*wv.y; a12 += x1*wv.z; a13 += x1*wv.w;
        }
        __syncthreads();
    }
    int gr0 = row0 + r0;
    if (gr0 < n) {
        float4 v = {a00,a01,a02,a03};
        *(float4*)&H[(size_t)gr0 * DIM + c0] = v;
    }
    if (gr0 + 1 < n) {
        float4 v = {a10,a11,a12,a13};
        *(float4*)&H[(size_t)(gr0 + 1) * DIM + c0] = v;
    }
}

// ---------------------------------------------------------------------------
// 2) per-node scores: Hs[n,h] = <H[n,h,:], AL[h,:]>, Ht likewise
// ---------------------------------------------------------------------------
__global__ __launch_bounds__(256) void scores_kernel(
    const float* __restrict__ H, const float* __restrict__ AL,
    const float* __restrict__ AR, float* __restrict__ Hs, float* __restrict__ Ht,
    int n)
{
    __shared__ float sAL[HEADS * ODIM], sAR[HEADS * ODIM];
    int t = threadIdx.x;
    if (t < HEADS * ODIM) { sAL[t] = AL[t]; sAR[t] = AR[t]; }
    __syncthreads();
    int idx = blockIdx.x * 256 + t;
    if (idx >= n * HEADS) return;
    int h = idx & (HEADS - 1);
    int node = idx >> 2;
    const float* hp = &H[(size_t)node * DIM + h * ODIM];
    float s = 0.f, s2 = 0.f;
    #pragma unroll
    for (int d = 0; d < ODIM; d += 4) {
        float4 v = *(const float4*)&hp[d];
        s  += v.x*sAL[h*ODIM+d] + v.y*sAL[h*ODIM+d+1] + v.z*sAL[h*ODIM+d+2] + v.w*sAL[h*ODIM+d+3];
        s2 += v.x*sAR[h*ODIM+d] + v.y*sAR[h*ODIM+d+1] + v.z*sAR[h*ODIM+d+2] + v.w*sAR[h*ODIM+d+3];
    }
    Hs[idx] = s; Ht[idx] = s2;
}

// ---------------------------------------------------------------------------
// 3) out-degree histogram by src (int atomics on 200KB table -> L2)
// ---------------------------------------------------------------------------
__global__ __launch_bounds__(256) void hist_kernel(
    const int* __restrict__ ei, int* __restrict__ cnt, int E, int n)
{
    int e = blockIdx.x * 256 + threadIdx.x;
    if (e >= E) return;
    int src = ei[e];
    src = max(0, min(src, n - 1));
    atomicAdd(&cnt[src], 1);
}

// ---------------------------------------------------------------------------
// 4) exclusive scan of counts -> offsets + fill cursors (1 block, 1024 thr)
// ---------------------------------------------------------------------------
__global__ __launch_bounds__(1024) void scan_kernel(
    const int* __restrict__ cnt, int* __restrict__ off,
    int* __restrict__ cursor, int n)
{
    __shared__ int s[1024];
    int t = threadIdx.x;
    int chunk = (n + 1023) >> 10;
    int lo = min(t * chunk, n), hi = min(lo + chunk, n);
    int sum = 0;
    for (int i = lo; i < hi; ++i) sum += cnt[i];
    s[t] = sum;
    __syncthreads();
    for (int ofs = 1; ofs < 1024; ofs <<= 1) {
        int v = 0;
        if (t >= ofs) v = s[t - ofs];
        __syncthreads();
        s[t] += v;
        __syncthreads();
    }
    int run = (t == 0) ? 0 : s[t - 1];
    for (int i = lo; i < hi; ++i) {
        off[i] = run; cursor[i] = run;
        run += cnt[i];
    }
    if (t == 1023) off[n] = s[1023];
}

// ---------------------------------------------------------------------------
// 5) fill CSR: csr_tgt[pos] = tgt at atomic cursor slot of src
// ---------------------------------------------------------------------------
__global__ __launch_bounds__(256) void fill_kernel(
    const int* __restrict__ ei, int* __restrict__ cursor,
    int* __restrict__ csr_tgt, int E, int n)
{
    int e = blockIdx.x * 256 + threadIdx.x;
    if (e >= E) return;
    int src = ei[e];
    int tgt = ei[E + e];
    src = max(0, min(src, n - 1));
    tgt = max(0, min(tgt, n - 1));
    int pos = atomicAdd(&cursor[src], 1);
    if (pos >= 0 && pos < E) csr_tgt[pos] = tgt;
}

// ---------------------------------------------------------------------------
// 6) CSR-gather aggregation: one wave per src node, zero fp32 atomics.
//    lane L: dims 2L,2L+1 (head h=L>>4). w recomputed from L2-resident Ht.
//    out[src,:] = elu( (sum w*H[tgt,:]) / (sum w + 1e-8) )  -> fp32 float2
// ---------------------------------------------------------------------------
__global__ __launch_bounds__(256) void agg_kernel(
    const float2* __restrict__ H2, const float* __restrict__ Hs,
    const float* __restrict__ Ht, const int* __restrict__ off,
    const int* __restrict__ csr_tgt, float2* __restrict__ out, int n, int E)
{
    int node = (blockIdx.x * 256 + threadIdx.x) >> 6;
    int L = threadIdx.x & 63;
    if (node >= n) return;
    int lo = off[node], hi = off[node + 1];
    lo = max(0, min(lo, E));
    hi = max(lo, min(hi, E));
    int h = L >> 4;
    float hs = Hs[node * HEADS + h];
    float ax = 0.f, ay = 0.f, S = 0.f;
    for (int i = lo; i < hi; ++i) {
        int tgt = csr_tgt[i];              // wave-uniform -> L1 broadcast
        float e = hs + Ht[tgt * HEADS + h];
        float lr = e > 0.f ? e : LRELU * e;
        float w = __expf(fminf(lr, 30.f));
        float2 v = H2[(size_t)tgt * 64 + L];
        ax += w * v.x;
        ay += w * v.y;
        S += w;
    }
    float inv = 1.f / (S + 1e-8f);
    float ox = ax * inv, oy = ay * inv;
    ox = ox > 0.f ? ox : (__expf(ox) - 1.f);
    oy = oy > 0.f ? oy : (__expf(oy) - 1.f);
    out[(size_t)node * 64 + L] = {ox, oy};
}

// ---------------------------------------------------------------------------
extern "C" void kernel_launch(void* const* d_in, const int* in_sizes, int n_in,
                              void* d_out, int out_size, void* d_ws, size_t ws_size,
                              hipStream_t stream) {
    const float* X  = (const float*)d_in[0];   // fp32
    const int*   EI = (const int*)d_in[1];     // int32[2E] block layout
    const float* W  = (const float*)d_in[2];   // fp32 row-major
    const float* AL = (const float*)d_in[3];
    const float* AR = (const float*)d_in[4];
    const int n = in_sizes[0] / DIM;      // 50000
    const int E = in_sizes[1] / 2;        // 1600000

    char* ws = (char*)d_ws;
    size_t o = 0;
    auto alloc = [&](size_t bytes) -> void* {
        o = (o + 255) & ~(size_t)255;
        void* p = ws + o;
        o += bytes;
        return p;
    };
    // total ~34.4 MB
    int*   cnt     = (int*)alloc((size_t)n * 4);
    int*   off     = (int*)alloc((size_t)(n + 1) * 4);
    int*   cursor  = (int*)alloc((size_t)n * 4);
    float* Hs      = (float*)alloc((size_t)n * HEADS * 4);
    float* Ht      = (float*)alloc((size_t)n * HEADS * 4);
    int*   csr_tgt = (int*)alloc((size_t)E * 4);
    float* H       = (float*)alloc((size_t)n * DIM * 4);

    hipMemsetAsync(cnt, 0, (size_t)n * 4, stream);

    proj_kernel<<<(n + 15) / 16, 256, 0, stream>>>(X, W, H, n);
    scores_kernel<<<(n * HEADS + 255) / 256, 256, 0, stream>>>(H, AL, AR, Hs, Ht, n);
    hist_kernel<<<(E + 255) / 256, 256, 0, stream>>>(EI, cnt, E, n);
    scan_kernel<<<1, 1024, 0, stream>>>(cnt, off, cursor, n);
    fill_kernel<<<(E + 255) / 256, 256, 0, stream>>>(EI, cursor, csr_tgt, E, n);
    agg_kernel<<<(n + 3) / 4, 256, 0, stream>>>(
        (const float2*)H, Hs, Ht, off, csr_tgt, (float2*)d_out, n, E);
}

// Round 13
// 490.204 us; speedup vs baseline: 3.0843x; 1.2097x over previous
//
#include <hip/hip_runtime.h>

#define DIM 128
#define HEADS 4
#define ODIM 32
#define LRELU 0.2f

// ---------------------------------------------------------------------------
// 1) H = X @ W (fp32, row-major). 16 rows/block, k-tiled, 36KB LDS.
// ---------------------------------------------------------------------------
__global__ __launch_bounds__(256) void proj_kernel(
    const float* __restrict__ X, const float* __restrict__ W,
    float* __restrict__ H, int n)
{
    __shared__ alignas(16) float sW[64 * DIM];   // 32 KB
    __shared__ alignas(16) float sX[16][64];     // 4 KB
    const int t = threadIdx.x;
    const int row0 = blockIdx.x * 16;
    const int c0 = (t & 31) * 4;
    const int r0 = (t >> 5) * 2;
    float a00=0,a01=0,a02=0,a03=0, a10=0,a11=0,a12=0,a13=0;

    for (int k0 = 0; k0 < DIM; k0 += 64) {
        #pragma unroll
        for (int i = 0; i < 8; ++i) {
            int idx = (i * 256 + t) * 4;
            *(float4*)&sW[idx] = *(const float4*)&W[k0 * DIM + idx];
        }
        {
            int idx = t * 4;
            int r = idx >> 6, k = idx & 63;
            int gr = row0 + r;
            float4 v = {0.f, 0.f, 0.f, 0.f};
            if (gr < n) v = *(const float4*)&X[(size_t)gr * DIM + k0 + k];
            *(float4*)&sX[r][k] = v;
        }
        __syncthreads();
        #pragma unroll 8
        for (int k = 0; k < 64; ++k) {
            float x0 = sX[r0][k], x1 = sX[r0 + 1][k];
            float4 wv = *(const float4*)&sW[k * DIM + c0];
            a00 += x0*wv.x; a01 += x0*wv.y; a02 += x0*wv.z; a03 += x0*wv.w;
            a10 += x1*wv.x; a11 += x1*wv.y; a12 += x1*wv.z; a13 += x1*wv.w;
        }
        __syncthreads();
    }
    int gr0 = row0 + r0;
    if (gr0 < n) {
        float4 v = {a00,a01,a02,a03};
        *(float4*)&H[(size_t)gr0 * DIM + c0] = v;
    }
    if (gr0 + 1 < n) {
        float4 v = {a10,a11,a12,a13};
        *(float4*)&H[(size_t)(gr0 + 1) * DIM + c0] = v;
    }
}

// ---------------------------------------------------------------------------
// 2) per-node scores: Hs[n,h] = <H[n,h,:], AL[h,:]>, Ht likewise
// ---------------------------------------------------------------------------
__global__ __launch_bounds__(256) void scores_kernel(
    const float* __restrict__ H, const float* __restrict__ AL,
    const float* __restrict__ AR, float* __restrict__ Hs, float* __restrict__ Ht,
    int n)
{
    __shared__ float sAL[HEADS * ODIM], sAR[HEADS * ODIM];
    int t = threadIdx.x;
    if (t < HEADS * ODIM) { sAL[t] = AL[t]; sAR[t] = AR[t]; }
    __syncthreads();
    int idx = blockIdx.x * 256 + t;
    if (idx >= n * HEADS) return;
    int h = idx & (HEADS - 1);
    int node = idx >> 2;
    const float* hp = &H[(size_t)node * DIM + h * ODIM];
    float s = 0.f, s2 = 0.f;
    #pragma unroll
    for (int d = 0; d < ODIM; d += 4) {
        float4 v = *(const float4*)&hp[d];
        s  += v.x*sAL[h*ODIM+d] + v.y*sAL[h*ODIM+d+1] + v.z*sAL[h*ODIM+d+2] + v.w*sAL[h*ODIM+d+3];
        s2 += v.x*sAR[h*ODIM+d] + v.y*sAR[h*ODIM+d+1] + v.z*sAR[h*ODIM+d+2] + v.w*sAR[h*ODIM+d+3];
    }
    Hs[idx] = s; Ht[idx] = s2;
}

// ---------------------------------------------------------------------------
// 3) out-degree histogram by src
// ---------------------------------------------------------------------------
__global__ __launch_bounds__(256) void hist_kernel(
    const int* __restrict__ ei, int* __restrict__ cnt, int E, int n)
{
    int e = blockIdx.x * 256 + threadIdx.x;
    if (e >= E) return;
    int src = ei[e];
    src = max(0, min(src, n - 1));
    atomicAdd(&cnt[src], 1);
}

// ---------------------------------------------------------------------------
// 4a) tile reduce: tsum[b] = sum of cnt[b*256 .. b*256+255]  (coalesced)
// ---------------------------------------------------------------------------
__global__ __launch_bounds__(256) void scan_reduce_kernel(
    const int* __restrict__ cnt, int* __restrict__ tsum, int n)
{
    __shared__ int s[256];
    int t = threadIdx.x;
    int i = blockIdx.x * 256 + t;
    s[t] = (i < n) ? cnt[i] : 0;
    __syncthreads();
    for (int ofs = 128; ofs > 0; ofs >>= 1) {
        if (t < ofs) s[t] += s[t + ofs];
        __syncthreads();
    }
    if (t == 0) tsum[blockIdx.x] = s[0];
}

// ---------------------------------------------------------------------------
// 4b) scan tile sums (ntiles <= 256): tpre[b] = exclusive prefix of tsum
// ---------------------------------------------------------------------------
__global__ __launch_bounds__(256) void scan_tsums_kernel(
    const int* __restrict__ tsum, int* __restrict__ tpre, int ntiles)
{
    __shared__ int s[256];
    int t = threadIdx.x;
    int v = (t < ntiles) ? tsum[t] : 0;
    s[t] = v;
    __syncthreads();
    for (int ofs = 1; ofs < 256; ofs <<= 1) {
        int x = (t >= ofs) ? s[t - ofs] : 0;
        __syncthreads();
        s[t] += x;
        __syncthreads();
    }
    if (t < ntiles) tpre[t] = s[t] - v;   // exclusive
}

// ---------------------------------------------------------------------------
// 4c) expand: off[i] = cursor[i] = tpre[b] + intra-tile exclusive prefix
// ---------------------------------------------------------------------------
__global__ __launch_bounds__(256) void scan_expand_kernel(
    const int* __restrict__ cnt, const int* __restrict__ tpre,
    int* __restrict__ off, int* __restrict__ cursor, int n, int E)
{
    __shared__ int s[256];
    int t = threadIdx.x;
    int i = blockIdx.x * 256 + t;
    int v = (i < n) ? cnt[i] : 0;
    s[t] = v;
    __syncthreads();
    for (int ofs = 1; ofs < 256; ofs <<= 1) {
        int x = (t >= ofs) ? s[t - ofs] : 0;
        __syncthreads();
        s[t] += x;
        __syncthreads();
    }
    if (i < n) {
        int p = tpre[blockIdx.x] + s[t] - v;
        off[i] = p;
        cursor[i] = p;
    }
    if (i == 0) off[n] = E;   // every (clamped) edge lands in some counter
}

// ---------------------------------------------------------------------------
// 5) fill CSR: csr_tgt[pos] = tgt at atomic cursor slot of src
// ---------------------------------------------------------------------------
__global__ __launch_bounds__(256) void fill_kernel(
    const int* __restrict__ ei, int* __restrict__ cursor,
    int* __restrict__ csr_tgt, int E, int n)
{
    int e = blockIdx.x * 256 + threadIdx.x;
    if (e >= E) return;
    int src = ei[e];
    int tgt = ei[E + e];
    src = max(0, min(src, n - 1));
    tgt = max(0, min(tgt, n - 1));
    int pos = atomicAdd(&cursor[src], 1);
    if (pos >= 0 && pos < E) csr_tgt[pos] = tgt;
}

// ---------------------------------------------------------------------------
// 6) CSR-gather aggregation: one wave per src node, zero fp32 atomics.
// ---------------------------------------------------------------------------
__global__ __launch_bounds__(256) void agg_kernel(
    const float2* __restrict__ H2, const float* __restrict__ Hs,
    const float* __restrict__ Ht, const int* __restrict__ off,
    const int* __restrict__ csr_tgt, float2* __restrict__ out, int n, int E)
{
    int node = (blockIdx.x * 256 + threadIdx.x) >> 6;
    int L = threadIdx.x & 63;
    if (node >= n) return;
    int lo = off[node], hi = off[node + 1];
    lo = max(0, min(lo, E));
    hi = max(lo, min(hi, E));
    int h = L >> 4;
    float hs = Hs[node * HEADS + h];
    float ax = 0.f, ay = 0.f, S = 0.f;
    for (int i = lo; i < hi; ++i) {
        int tgt = csr_tgt[i];              // wave-uniform
        float e = hs + Ht[tgt * HEADS + h];
        float lr = e > 0.f ? e : LRELU * e;
        float w = __expf(fminf(lr, 30.f));
        float2 v = H2[(size_t)tgt * 64 + L];
        ax += w * v.x;
        ay += w * v.y;
        S += w;
    }
    float inv = 1.f / (S + 1e-8f);
    float ox = ax * inv, oy = ay * inv;
    ox = ox > 0.f ? ox : (__expf(ox) - 1.f);
    oy = oy > 0.f ? oy : (__expf(oy) - 1.f);
    out[(size_t)node * 64 + L] = {ox, oy};
}

// ---------------------------------------------------------------------------
extern "C" void kernel_launch(void* const* d_in, const int* in_sizes, int n_in,
                              void* d_out, int out_size, void* d_ws, size_t ws_size,
                              hipStream_t stream) {
    const float* X  = (const float*)d_in[0];   // fp32
    const int*   EI = (const int*)d_in[1];     // int32[2E] block layout
    const float* W  = (const float*)d_in[2];   // fp32 row-major
    const float* AL = (const float*)d_in[3];
    const float* AR = (const float*)d_in[4];
    const int n = in_sizes[0] / DIM;      // 50000
    const int E = in_sizes[1] / 2;        // 1600000
    const int ntiles = (n + 255) / 256;   // 196

    char* ws = (char*)d_ws;
    size_t o = 0;
    auto alloc = [&](size_t bytes) -> void* {
        o = (o + 255) & ~(size_t)255;
        void* p = ws + o;
        o += bytes;
        return p;
    };
    int*   cnt     = (int*)alloc((size_t)n * 4);
    int*   off     = (int*)alloc((size_t)(n + 1) * 4);
    int*   cursor  = (int*)alloc((size_t)n * 4);
    int*   tsum    = (int*)alloc((size_t)ntiles * 4);
    int*   tpre    = (int*)alloc((size_t)ntiles * 4);
    float* Hs      = (float*)alloc((size_t)n * HEADS * 4);
    float* Ht      = (float*)alloc((size_t)n * HEADS * 4);
    int*   csr_tgt = (int*)alloc((size_t)E * 4);
    float* H       = (float*)alloc((size_t)n * DIM * 4);

    hipMemsetAsync(cnt, 0, (size_t)n * 4, stream);

    proj_kernel<<<(n + 15) / 16, 256, 0, stream>>>(X, W, H, n);
    scores_kernel<<<(n * HEADS + 255) / 256, 256, 0, stream>>>(H, AL, AR, Hs, Ht, n);
    hist_kernel<<<(E + 255) / 256, 256, 0, stream>>>(EI, cnt, E, n);
    scan_reduce_kernel<<<ntiles, 256, 0, stream>>>(cnt, tsum, n);
    scan_tsums_kernel<<<1, 256, 0, stream>>>(tsum, tpre, ntiles);
    scan_expand_kernel<<<ntiles, 256, 0, stream>>>(cnt, tpre, off, cursor, n, E);
    fill_kernel<<<(E + 255) / 256, 256, 0, stream>>>(EI, cursor, csr_tgt, E, n);
    agg_kernel<<<(n + 3) / 4, 256, 0, stream>>>(
        (const float2*)H, Hs, Ht, off, csr_tgt, (float2*)d_out, n, E);
}

// Round 14
// 373.650 us; speedup vs baseline: 4.0464x; 1.3119x over previous
//
#include <hip/hip_runtime.h>

#define DIM 128
#define HEADS 4
#define ODIM 32
#define LRELU 0.2f

typedef unsigned int u32;
typedef unsigned short u16;

__device__ __forceinline__ u16 f2bf(float f) {
    union { u32 u; float f; } x; x.f = f;
    u32 u = x.u;
    u32 r = u + 0x7FFFu + ((u >> 16) & 1u);
    return (u16)(r >> 16);
}
__device__ __forceinline__ float blo(u32 b) {   // low bf16 -> fp32
    union { u32 u; float f; } x; x.u = b << 16; return x.f;
}
__device__ __forceinline__ float bhi(u32 b) {   // high bf16 -> fp32
    union { u32 u; float f; } x; x.u = b & 0xFFFF0000u; return x.f;
}

// ---------------------------------------------------------------------------
// 1) H = X @ W (fp32 accum), output packed bf16x2: Hb[node*64 + d/2]
//    16 rows/block, k-tiled, 36KB LDS.
// ---------------------------------------------------------------------------
__global__ __launch_bounds__(256) void proj_kernel(
    const float* __restrict__ X, const float* __restrict__ W,
    u32* __restrict__ Hb, int n)
{
    __shared__ alignas(16) float sW[64 * DIM];   // 32 KB
    __shared__ alignas(16) float sX[16][64];     // 4 KB
    const int t = threadIdx.x;
    const int row0 = blockIdx.x * 16;
    const int c0 = (t & 31) * 4;
    const int r0 = (t >> 5) * 2;
    float a00=0,a01=0,a02=0,a03=0, a10=0,a11=0,a12=0,a13=0;

    for (int k0 = 0; k0 < DIM; k0 += 64) {
        #pragma unroll
        for (int i = 0; i < 8; ++i) {
            int idx = (i * 256 + t) * 4;
            *(float4*)&sW[idx] = *(const float4*)&W[k0 * DIM + idx];
        }
        {
            int idx = t * 4;
            int r = idx >> 6, k = idx & 63;
            int gr = row0 + r;
            float4 v = {0.f, 0.f, 0.f, 0.f};
            if (gr < n) v = *(const float4*)&X[(size_t)gr * DIM + k0 + k];
            *(float4*)&sX[r][k] = v;
        }
        __syncthreads();
        #pragma unroll 8
        for (int k = 0; k < 64; ++k) {
            float x0 = sX[r0][k], x1 = sX[r0 + 1][k];
            float4 wv = *(const float4*)&sW[k * DIM + c0];
            a00 += x0*wv.x; a01 += x0*wv.y; a02 += x0*wv.z; a03 += x0*wv.w;
            a10 += x1*wv.x; a11 += x1*wv.y; a12 += x1*wv.z; a13 += x1*wv.w;
        }
        __syncthreads();
    }
    int gr0 = row0 + r0;
    int d2 = c0 >> 1;                          // u32 index of first dim pair
    if (gr0 < n) {
        uint2 p;
        p.x = ((u32)f2bf(a01) << 16) | (u32)f2bf(a00);
        p.y = ((u32)f2bf(a03) << 16) | (u32)f2bf(a02);
        *(uint2*)&Hb[(size_t)gr0 * 64 + d2] = p;
    }
    if (gr0 + 1 < n) {
        uint2 p;
        p.x = ((u32)f2bf(a11) << 16) | (u32)f2bf(a10);
        p.y = ((u32)f2bf(a13) << 16) | (u32)f2bf(a12);
        *(uint2*)&Hb[(size_t)(gr0 + 1) * 64 + d2] = p;
    }
}

// ---------------------------------------------------------------------------
// 2) per-node scores from bf16 Hb: Hs[n,h]=<H[n,h,:],AL[h,:]>, Ht likewise
// ---------------------------------------------------------------------------
__global__ __launch_bounds__(256) void scores_kernel(
    const u32* __restrict__ Hb, const float* __restrict__ AL,
    const float* __restrict__ AR, float* __restrict__ Hs, float* __restrict__ Ht,
    int n)
{
    __shared__ float sAL[HEADS * ODIM], sAR[HEADS * ODIM];
    int t = threadIdx.x;
    if (t < HEADS * ODIM) { sAL[t] = AL[t]; sAR[t] = AR[t]; }
    __syncthreads();
    int idx = blockIdx.x * 256 + t;
    if (idx >= n * HEADS) return;
    int h = idx & (HEADS - 1);
    int node = idx >> 2;
    const u32* hp = &Hb[(size_t)node * 64 + h * (ODIM / 2)];
    float s = 0.f, s2 = 0.f;
    #pragma unroll
    for (int q = 0; q < ODIM / 2; q += 2) {
        uint2 b = *(const uint2*)&hp[q];
        float v0 = blo(b.x), v1 = bhi(b.x), v2 = blo(b.y), v3 = bhi(b.y);
        int d = q * 2;
        s  += v0*sAL[h*ODIM+d] + v1*sAL[h*ODIM+d+1] + v2*sAL[h*ODIM+d+2] + v3*sAL[h*ODIM+d+3];
        s2 += v0*sAR[h*ODIM+d] + v1*sAR[h*ODIM+d+1] + v2*sAR[h*ODIM+d+2] + v3*sAR[h*ODIM+d+3];
    }
    Hs[idx] = s; Ht[idx] = s2;
}

// ---------------------------------------------------------------------------
// 3) out-degree histogram by src
// ---------------------------------------------------------------------------
__global__ __launch_bounds__(256) void hist_kernel(
    const int* __restrict__ ei, int* __restrict__ cnt, int E, int n)
{
    int e = blockIdx.x * 256 + threadIdx.x;
    if (e >= E) return;
    int src = ei[e];
    src = max(0, min(src, n - 1));
    atomicAdd(&cnt[src], 1);
}

// ---------------------------------------------------------------------------
// 4a) tile reduce (coalesced)
// ---------------------------------------------------------------------------
__global__ __launch_bounds__(256) void scan_reduce_kernel(
    const int* __restrict__ cnt, int* __restrict__ tsum, int n)
{
    __shared__ int s[256];
    int t = threadIdx.x;
    int i = blockIdx.x * 256 + t;
    s[t] = (i < n) ? cnt[i] : 0;
    __syncthreads();
    for (int ofs = 128; ofs > 0; ofs >>= 1) {
        if (t < ofs) s[t] += s[t + ofs];
        __syncthreads();
    }
    if (t == 0) tsum[blockIdx.x] = s[0];
}

// ---------------------------------------------------------------------------
// 4b) scan tile sums (ntiles <= 256)
// ---------------------------------------------------------------------------
__global__ __launch_bounds__(256) void scan_tsums_kernel(
    const int* __restrict__ tsum, int* __restrict__ tpre, int ntiles)
{
    __shared__ int s[256];
    int t = threadIdx.x;
    int v = (t < ntiles) ? tsum[t] : 0;
    s[t] = v;
    __syncthreads();
    for (int ofs = 1; ofs < 256; ofs <<= 1) {
        int x = (t >= ofs) ? s[t - ofs] : 0;
        __syncthreads();
        s[t] += x;
        __syncthreads();
    }
    if (t < ntiles) tpre[t] = s[t] - v;   // exclusive
}

// ---------------------------------------------------------------------------
// 4c) expand to off/cursor (coalesced)
// ---------------------------------------------------------------------------
__global__ __launch_bounds__(256) void scan_expand_kernel(
    const int* __restrict__ cnt, const int* __restrict__ tpre,
    int* __restrict__ off, int* __restrict__ cursor, int n, int E)
{
    __shared__ int s[256];
    int t = threadIdx.x;
    int i = blockIdx.x * 256 + t;
    int v = (i < n) ? cnt[i] : 0;
    s[t] = v;
    __syncthreads();
    for (int ofs = 1; ofs < 256; ofs <<= 1) {
        int x = (t >= ofs) ? s[t - ofs] : 0;
        __syncthreads();
        s[t] += x;
        __syncthreads();
    }
    if (i < n) {
        int p = tpre[blockIdx.x] + s[t] - v;
        off[i] = p;
        cursor[i] = p;
    }
    if (i == 0) off[n] = E;
}

// ---------------------------------------------------------------------------
// 5) fill CSR: csr_tgt[pos] = tgt at atomic cursor slot of src
// ---------------------------------------------------------------------------
__global__ __launch_bounds__(256) void fill_kernel(
    const int* __restrict__ ei, int* __restrict__ cursor,
    int* __restrict__ csr_tgt, int E, int n)
{
    int e = blockIdx.x * 256 + threadIdx.x;
    if (e >= E) return;
    int src = ei[e];
    int tgt = ei[E + e];
    src = max(0, min(src, n - 1));
    tgt = max(0, min(tgt, n - 1));
    int pos = atomicAdd(&cursor[src], 1);
    if (pos >= 0 && pos < E) csr_tgt[pos] = tgt;
}

// ---------------------------------------------------------------------------
// 6) CSR-gather aggregation, bf16 payload, 4x unrolled for MLP.
//    lane L: dims 2L,2L+1 (head h=L>>4); one wave per src node.
// ---------------------------------------------------------------------------
__global__ __launch_bounds__(256) void agg_kernel(
    const u32* __restrict__ Hb, const float* __restrict__ Hs,
    const float* __restrict__ Ht, const int* __restrict__ off,
    const int* __restrict__ csr_tgt, float2* __restrict__ out, int n, int E)
{
    int node = (blockIdx.x * 256 + threadIdx.x) >> 6;
    int L = threadIdx.x & 63;
    if (node >= n) return;
    int lo = off[node], hi = off[node + 1];
    lo = max(0, min(lo, E));
    hi = max(lo, min(hi, E));
    int h = L >> 4;
    float hs = Hs[node * HEADS + h];
    float ax = 0.f, ay = 0.f, S = 0.f;

    int i = lo;
    for (; i + 4 <= hi; i += 4) {
        int t0 = csr_tgt[i];
        int t1 = csr_tgt[i + 1];
        int t2 = csr_tgt[i + 2];
        int t3 = csr_tgt[i + 3];
        float e0 = hs + Ht[t0 * HEADS + h];
        float e1 = hs + Ht[t1 * HEADS + h];
        float e2 = hs + Ht[t2 * HEADS + h];
        float e3 = hs + Ht[t3 * HEADS + h];
        u32 b0 = Hb[(size_t)t0 * 64 + L];
        u32 b1 = Hb[(size_t)t1 * 64 + L];
        u32 b2 = Hb[(size_t)t2 * 64 + L];
        u32 b3 = Hb[(size_t)t3 * 64 + L];
        float w0 = __expf(fminf(e0 > 0.f ? e0 : LRELU * e0, 30.f));
        float w1 = __expf(fminf(e1 > 0.f ? e1 : LRELU * e1, 30.f));
        float w2 = __expf(fminf(e2 > 0.f ? e2 : LRELU * e2, 30.f));
        float w3 = __expf(fminf(e3 > 0.f ? e3 : LRELU * e3, 30.f));
        ax += w0 * blo(b0) + w1 * blo(b1) + w2 * blo(b2) + w3 * blo(b3);
        ay += w0 * bhi(b0) + w1 * bhi(b1) + w2 * bhi(b2) + w3 * bhi(b3);
        S  += (w0 + w1) + (w2 + w3);
    }
    for (; i < hi; ++i) {
        int tgt = csr_tgt[i];
        float e = hs + Ht[tgt * HEADS + h];
        float w = __expf(fminf(e > 0.f ? e : LRELU * e, 30.f));
        u32 b = Hb[(size_t)tgt * 64 + L];
        ax += w * blo(b);
        ay += w * bhi(b);
        S += w;
    }
    float inv = 1.f / (S + 1e-8f);
    float ox = ax * inv, oy = ay * inv;
    ox = ox > 0.f ? ox : (__expf(ox) - 1.f);
    oy = oy > 0.f ? oy : (__expf(oy) - 1.f);
    out[(size_t)node * 64 + L] = {ox, oy};
}

// ---------------------------------------------------------------------------
extern "C" void kernel_launch(void* const* d_in, const int* in_sizes, int n_in,
                              void* d_out, int out_size, void* d_ws, size_t ws_size,
                              hipStream_t stream) {
    const float* X  = (const float*)d_in[0];   // fp32
    const int*   EI = (const int*)d_in[1];     // int32[2E] block layout
    const float* W  = (const float*)d_in[2];   // fp32 row-major
    const float* AL = (const float*)d_in[3];
    const float* AR = (const float*)d_in[4];
    const int n = in_sizes[0] / DIM;      // 50000
    const int E = in_sizes[1] / 2;        // 1600000
    const int ntiles = (n + 255) / 256;   // 196

    char* ws = (char*)d_ws;
    size_t o = 0;
    auto alloc = [&](size_t bytes) -> void* {
        o = (o + 255) & ~(size_t)255;
        void* p = ws + o;
        o += bytes;
        return p;
    };
    // total ~21.6 MB
    int*   cnt     = (int*)alloc((size_t)n * 4);
    int*   off     = (int*)alloc((size_t)(n + 1) * 4);
    int*   cursor  = (int*)alloc((size_t)n * 4);
    int*   tsum    = (int*)alloc((size_t)ntiles * 4);
    int*   tpre    = (int*)alloc((size_t)ntiles * 4);
    float* Hs      = (float*)alloc((size_t)n * HEADS * 4);
    float* Ht      = (float*)alloc((size_t)n * HEADS * 4);
    int*   csr_tgt = (int*)alloc((size_t)E * 4);
    u32*   Hb      = (u32*)alloc((size_t)n * 64 * 4);   // bf16x2-packed H

    hipMemsetAsync(cnt, 0, (size_t)n * 4, stream);

    proj_kernel<<<(n + 15) / 16, 256, 0, stream>>>(X, W, Hb, n);
    scores_kernel<<<(n * HEADS + 255) / 256, 256, 0, stream>>>(Hb, AL, AR, Hs, Ht, n);
    hist_kernel<<<(E + 255) / 256, 256, 0, stream>>>(EI, cnt, E, n);
    scan_reduce_kernel<<<ntiles, 256, 0, stream>>>(cnt, tsum, n);
    scan_tsums_kernel<<<1, 256, 0, stream>>>(tsum, tpre, ntiles);
    scan_expand_kernel<<<ntiles, 256, 0, stream>>>(cnt, tpre, off, cursor, n, E);
    fill_kernel<<<(E + 255) / 256, 256, 0, stream>>>(EI, cursor, csr_tgt, E, n);
    agg_kernel<<<(n + 3) / 4, 256, 0, stream>>>(
        Hb, Hs, Ht, off, csr_tgt, (float2*)d_out, n, E);
}

// Round 15
// 327.702 us; speedup vs baseline: 4.6138x; 1.1402x over previous
//
#include <hip/hip_runtime.h>

#define DIM 128
#define HEADS 4
#define ODIM 32
#define LRELU 0.2f

typedef unsigned int u32;
typedef unsigned short u16;

__device__ __forceinline__ u16 f2bf(float f) {
    union { u32 u; float f; } x; x.f = f;
    u32 u = x.u;
    u32 r = u + 0x7FFFu + ((u >> 16) & 1u);
    return (u16)(r >> 16);
}
__device__ __forceinline__ float blo(u32 b) {   // low bf16 -> fp32
    union { u32 u; float f; } x; x.u = b << 16; return x.f;
}
__device__ __forceinline__ float bhi(u32 b) {   // high bf16 -> fp32
    union { u32 u; float f; } x; x.u = b & 0xFFFF0000u; return x.f;
}

// ---------------------------------------------------------------------------
// 1) H = X @ W (fp32 accum), output packed bf16x2: Hb[node*64 + d/2]
// ---------------------------------------------------------------------------
__global__ __launch_bounds__(256) void proj_kernel(
    const float* __restrict__ X, const float* __restrict__ W,
    u32* __restrict__ Hb, int n)
{
    __shared__ alignas(16) float sW[64 * DIM];   // 32 KB
    __shared__ alignas(16) float sX[16][64];     // 4 KB
    const int t = threadIdx.x;
    const int row0 = blockIdx.x * 16;
    const int c0 = (t & 31) * 4;
    const int r0 = (t >> 5) * 2;
    float a00=0,a01=0,a02=0,a03=0, a10=0,a11=0,a12=0,a13=0;

    for (int k0 = 0; k0 < DIM; k0 += 64) {
        #pragma unroll
        for (int i = 0; i < 8; ++i) {
            int idx = (i * 256 + t) * 4;
            *(float4*)&sW[idx] = *(const float4*)&W[k0 * DIM + idx];
        }
        {
            int idx = t * 4;
            int r = idx >> 6, k = idx & 63;
            int gr = row0 + r;
            float4 v = {0.f, 0.f, 0.f, 0.f};
            if (gr < n) v = *(const float4*)&X[(size_t)gr * DIM + k0 + k];
            *(float4*)&sX[r][k] = v;
        }
        __syncthreads();
        #pragma unroll 8
        for (int k = 0; k < 64; ++k) {
            float x0 = sX[r0][k], x1 = sX[r0 + 1][k];
            float4 wv = *(const float4*)&sW[k * DIM + c0];
            a00 += x0*wv.x; a01 += x0*wv.y; a02 += x0*wv.z; a03 += x0*wv.w;
            a10 += x1*wv.x; a11 += x1*wv.y; a12 += x1*wv.z; a13 += x1*wv.w;
        }
        __syncthreads();
    }
    int gr0 = row0 + r0;
    int d2 = c0 >> 1;
    if (gr0 < n) {
        uint2 p;
        p.x = ((u32)f2bf(a01) << 16) | (u32)f2bf(a00);
        p.y = ((u32)f2bf(a03) << 16) | (u32)f2bf(a02);
        *(uint2*)&Hb[(size_t)gr0 * 64 + d2] = p;
    }
    if (gr0 + 1 < n) {
        uint2 p;
        p.x = ((u32)f2bf(a11) << 16) | (u32)f2bf(a10);
        p.y = ((u32)f2bf(a13) << 16) | (u32)f2bf(a12);
        *(uint2*)&Hb[(size_t)(gr0 + 1) * 64 + d2] = p;
    }
}

// ---------------------------------------------------------------------------
// 2) per-node scores from bf16 Hb
// ---------------------------------------------------------------------------
__global__ __launch_bounds__(256) void scores_kernel(
    const u32* __restrict__ Hb, const float* __restrict__ AL,
    const float* __restrict__ AR, float* __restrict__ Hs, float* __restrict__ Ht,
    int n)
{
    __shared__ float sAL[HEADS * ODIM], sAR[HEADS * ODIM];
    int t = threadIdx.x;
    if (t < HEADS * ODIM) { sAL[t] = AL[t]; sAR[t] = AR[t]; }
    __syncthreads();
    int idx = blockIdx.x * 256 + t;
    if (idx >= n * HEADS) return;
    int h = idx & (HEADS - 1);
    int node = idx >> 2;
    const u32* hp = &Hb[(size_t)node * 64 + h * (ODIM / 2)];
    float s = 0.f, s2 = 0.f;
    #pragma unroll
    for (int q = 0; q < ODIM / 2; q += 2) {
        uint2 b = *(const uint2*)&hp[q];
        float v0 = blo(b.x), v1 = bhi(b.x), v2 = blo(b.y), v3 = bhi(b.y);
        int d = q * 2;
        s  += v0*sAL[h*ODIM+d] + v1*sAL[h*ODIM+d+1] + v2*sAL[h*ODIM+d+2] + v3*sAL[h*ODIM+d+3];
        s2 += v0*sAR[h*ODIM+d] + v1*sAR[h*ODIM+d+1] + v2*sAR[h*ODIM+d+2] + v3*sAR[h*ODIM+d+3];
    }
    Hs[idx] = s; Ht[idx] = s2;
}

// ---------------------------------------------------------------------------
// 3) out-degree histogram by src
// ---------------------------------------------------------------------------
__global__ __launch_bounds__(256) void hist_kernel(
    const int* __restrict__ ei, int* __restrict__ cnt, int E, int n)
{
    int e = blockIdx.x * 256 + threadIdx.x;
    if (e >= E) return;
    int src = ei[e];
    src = max(0, min(src, n - 1));
    atomicAdd(&cnt[src], 1);
}

// ---------------------------------------------------------------------------
// 4a) tile reduce: tsum[b] = sum cnt over 256-node bucket b (coalesced)
// ---------------------------------------------------------------------------
__global__ __launch_bounds__(256) void scan_reduce_kernel(
    const int* __restrict__ cnt, int* __restrict__ tsum, int n)
{
    __shared__ int s[256];
    int t = threadIdx.x;
    int i = blockIdx.x * 256 + t;
    s[t] = (i < n) ? cnt[i] : 0;
    __syncthreads();
    for (int ofs = 128; ofs > 0; ofs >>= 1) {
        if (t < ofs) s[t] += s[t + ofs];
        __syncthreads();
    }
    if (t == 0) tsum[blockIdx.x] = s[0];
}

// ---------------------------------------------------------------------------
// 4b) scan tile sums (ntiles <= 256): tpre = exclusive prefix; bcur = copy
// ---------------------------------------------------------------------------
__global__ __launch_bounds__(256) void scan_tsums_kernel(
    const int* __restrict__ tsum, int* __restrict__ tpre,
    int* __restrict__ bcur, int ntiles)
{
    __shared__ int s[256];
    int t = threadIdx.x;
    int v = (t < ntiles) ? tsum[t] : 0;
    s[t] = v;
    __syncthreads();
    for (int ofs = 1; ofs < 256; ofs <<= 1) {
        int x = (t >= ofs) ? s[t - ofs] : 0;
        __syncthreads();
        s[t] += x;
        __syncthreads();
    }
    if (t < ntiles) {
        int ex = s[t] - v;
        tpre[t] = ex;
        bcur[t] = ex;
    }
}

// ---------------------------------------------------------------------------
// 4c) expand to per-node off/cursor (coalesced)
// ---------------------------------------------------------------------------
__global__ __launch_bounds__(256) void scan_expand_kernel(
    const int* __restrict__ cnt, const int* __restrict__ tpre,
    int* __restrict__ off, int* __restrict__ cursor, int n, int E)
{
    __shared__ int s[256];
    int t = threadIdx.x;
    int i = blockIdx.x * 256 + t;
    int v = (i < n) ? cnt[i] : 0;
    s[t] = v;
    __syncthreads();
    for (int ofs = 1; ofs < 256; ofs <<= 1) {
        int x = (t >= ofs) ? s[t - ofs] : 0;
        __syncthreads();
        s[t] += x;
        __syncthreads();
    }
    if (i < n) {
        int p = tpre[blockIdx.x] + s[t] - v;
        off[i] = p;
        cursor[i] = p;
    }
    if (i == 0) off[n] = E;
}

// ---------------------------------------------------------------------------
// 5a) LDS-staged partition: group edges by bucket = src>>8 into part[],
//     key = (src&255)<<17 | tgt  (tgt < 2^17). Bucket-ordered LDS flush
//     gives ~84B contiguous runs -> near-line-granular writes.
// ---------------------------------------------------------------------------
#define PT 4096
__global__ __launch_bounds__(256) void partition_kernel(
    const int* __restrict__ ei, int* __restrict__ bcur,
    u32* __restrict__ part, int E, int n)
{
    __shared__ u32 stage[PT];                  // 16 KB
    __shared__ int lcnt[256], loff[256], lcur[256], gbase[256];
    const int t = threadIdx.x;
    const int base = blockIdx.x * PT;
    lcnt[t] = 0;
    __syncthreads();

    u32 key[16];
    int bkt[16];
    #pragma unroll
    for (int i = 0; i < 16; ++i) {
        int e = base + i * 256 + t;
        bkt[i] = -1;
        key[i] = 0;
        if (e < E) {
            int src = ei[e];
            int tgt = ei[E + e];
            src = max(0, min(src, n - 1));
            tgt = max(0, min(tgt, n - 1));
            bkt[i] = src >> 8;
            key[i] = ((u32)(src & 255) << 17) | (u32)tgt;
            atomicAdd(&lcnt[bkt[i]], 1);
        }
    }
    __syncthreads();
    // exclusive scan lcnt -> loff; lcur = loff
    {
        int v = lcnt[t];
        s_scan:;
        loff[t] = v;
        __syncthreads();
        for (int ofs = 1; ofs < 256; ofs <<= 1) {
            int x = (t >= ofs) ? loff[t - ofs] : 0;
            __syncthreads();
            loff[t] += x;
            __syncthreads();
        }
        int incl = loff[t];
        __syncthreads();
        loff[t] = incl - v;
        lcur[t] = incl - v;
    }
    __syncthreads();
    // place keys bucket-ordered in LDS
    #pragma unroll
    for (int i = 0; i < 16; ++i) {
        if (bkt[i] >= 0) {
            int p = atomicAdd(&lcur[bkt[i]], 1);
            stage[p] = key[i];
        }
    }
    // reserve global runs (one atomic per nonempty bucket)
    {
        int c = lcnt[t];
        gbase[t] = (c > 0) ? atomicAdd(&bcur[t], c) : 0;
    }
    __syncthreads();
    int total = loff[255] + lcnt[255];
    for (int i = t; i < total; i += 256) {
        // largest b with loff[b] <= i (empty buckets resolve correctly)
        int lo = 0, hi = 255;
        while (lo < hi) {
            int mid = (lo + hi + 1) >> 1;
            if (loff[mid] <= i) lo = mid; else hi = mid - 1;
        }
        part[gbase[lo] + (i - loff[lo])] = stage[i];
    }
}

// ---------------------------------------------------------------------------
// 5b) CSR fill from partition: one block per bucket -> all scattered writes
//     land in this bucket's ~32KB csr region on ONE CU/XCD -> L2-local.
// ---------------------------------------------------------------------------
__global__ __launch_bounds__(256) void csrfill_kernel(
    const u32* __restrict__ part, const int* __restrict__ tpre,
    const int* __restrict__ tsum, int* __restrict__ cursor,
    int* __restrict__ csr_tgt, int E)
{
    int b = blockIdx.x;
    int lo = tpre[b], cnt = tsum[b];
    for (int i = threadIdx.x; i < cnt; i += 256) {
        u32 key = part[lo + i];
        int src = (b << 8) | (int)(key >> 17);
        int tgt = (int)(key & 0x1FFFFu);
        int pos = atomicAdd(&cursor[src], 1);
        if (pos >= 0 && pos < E) csr_tgt[pos] = tgt;
    }
}

// ---------------------------------------------------------------------------
// 6) CSR-gather aggregation, bf16 payload, 4x unrolled. One wave per node.
// ---------------------------------------------------------------------------
__global__ __launch_bounds__(256) void agg_kernel(
    const u32* __restrict__ Hb, const float* __restrict__ Hs,
    const float* __restrict__ Ht, const int* __restrict__ off,
    const int* __restrict__ csr_tgt, float2* __restrict__ out, int n, int E)
{
    int node = (blockIdx.x * 256 + threadIdx.x) >> 6;
    int L = threadIdx.x & 63;
    if (node >= n) return;
    int lo = off[node], hi = off[node + 1];
    lo = max(0, min(lo, E));
    hi = max(lo, min(hi, E));
    int h = L >> 4;
    float hs = Hs[node * HEADS + h];
    float ax = 0.f, ay = 0.f, S = 0.f;

    int i = lo;
    for (; i + 4 <= hi; i += 4) {
        int t0 = csr_tgt[i];
        int t1 = csr_tgt[i + 1];
        int t2 = csr_tgt[i + 2];
        int t3 = csr_tgt[i + 3];
        float e0 = hs + Ht[t0 * HEADS + h];
        float e1 = hs + Ht[t1 * HEADS + h];
        float e2 = hs + Ht[t2 * HEADS + h];
        float e3 = hs + Ht[t3 * HEADS + h];
        u32 b0 = Hb[(size_t)t0 * 64 + L];
        u32 b1 = Hb[(size_t)t1 * 64 + L];
        u32 b2 = Hb[(size_t)t2 * 64 + L];
        u32 b3 = Hb[(size_t)t3 * 64 + L];
        float w0 = __expf(fminf(e0 > 0.f ? e0 : LRELU * e0, 30.f));
        float w1 = __expf(fminf(e1 > 0.f ? e1 : LRELU * e1, 30.f));
        float w2 = __expf(fminf(e2 > 0.f ? e2 : LRELU * e2, 30.f));
        float w3 = __expf(fminf(e3 > 0.f ? e3 : LRELU * e3, 30.f));
        ax += w0 * blo(b0) + w1 * blo(b1) + w2 * blo(b2) + w3 * blo(b3);
        ay += w0 * bhi(b0) + w1 * bhi(b1) + w2 * bhi(b2) + w3 * bhi(b3);
        S  += (w0 + w1) + (w2 + w3);
    }
    for (; i < hi; ++i) {
        int tgt = csr_tgt[i];
        float e = hs + Ht[tgt * HEADS + h];
        float w = __expf(fminf(e > 0.f ? e : LRELU * e, 30.f));
        u32 b = Hb[(size_t)tgt * 64 + L];
        ax += w * blo(b);
        ay += w * bhi(b);
        S += w;
    }
    float inv = 1.f / (S + 1e-8f);
    float ox = ax * inv, oy = ay * inv;
    ox = ox > 0.f ? ox : (__expf(ox) - 1.f);
    oy = oy > 0.f ? oy : (__expf(oy) - 1.f);
    out[(size_t)node * 64 + L] = {ox, oy};
}

// ---------------------------------------------------------------------------
extern "C" void kernel_launch(void* const* d_in, const int* in_sizes, int n_in,
                              void* d_out, int out_size, void* d_ws, size_t ws_size,
                              hipStream_t stream) {
    const float* X  = (const float*)d_in[0];   // fp32
    const int*   EI = (const int*)d_in[1];     // int32[2E] block layout
    const float* W  = (const float*)d_in[2];   // fp32 row-major
    const float* AL = (const float*)d_in[3];
    const float* AR = (const float*)d_in[4];
    const int n = in_sizes[0] / DIM;      // 50000
    const int E = in_sizes[1] / 2;        // 1600000
    const int ntiles = (n + 255) / 256;   // 196 (= bucket count)

    char* ws = (char*)d_ws;
    size_t o = 0;
    auto alloc = [&](size_t bytes) -> void* {
        o = (o + 255) & ~(size_t)255;
        void* p = ws + o;
        o += bytes;
        return p;
    };
    // total ~28.3 MB
    int*   cnt     = (int*)alloc((size_t)n * 4);
    int*   off     = (int*)alloc((size_t)(n + 1) * 4);
    int*   cursor  = (int*)alloc((size_t)n * 4);
    int*   tsum    = (int*)alloc(256 * 4);
    int*   tpre    = (int*)alloc(256 * 4);
    int*   bcur    = (int*)alloc(256 * 4);
    float* Hs      = (float*)alloc((size_t)n * HEADS * 4);
    float* Ht      = (float*)alloc((size_t)n * HEADS * 4);
    int*   csr_tgt = (int*)alloc((size_t)E * 4);
    u32*   part    = (u32*)alloc((size_t)E * 4);
    u32*   Hb      = (u32*)alloc((size_t)n * 64 * 4);

    hipMemsetAsync(cnt, 0, (size_t)n * 4, stream);

    proj_kernel<<<(n + 15) / 16, 256, 0, stream>>>(X, W, Hb, n);
    scores_kernel<<<(n * HEADS + 255) / 256, 256, 0, stream>>>(Hb, AL, AR, Hs, Ht, n);
    hist_kernel<<<(E + 255) / 256, 256, 0, stream>>>(EI, cnt, E, n);
    scan_reduce_kernel<<<ntiles, 256, 0, stream>>>(cnt, tsum, n);
    scan_tsums_kernel<<<1, 256, 0, stream>>>(tsum, tpre, bcur, ntiles);
    scan_expand_kernel<<<ntiles, 256, 0, stream>>>(cnt, tpre, off, cursor, n, E);
    partition_kernel<<<(E + PT - 1) / PT, 256, 0, stream>>>(EI, bcur, part, E, n);
    csrfill_kernel<<<ntiles, 256, 0, stream>>>(part, tpre, tsum, cursor, csr_tgt, E);
    agg_kernel<<<(n + 3) / 4, 256, 0, stream>>>(
        Hb, Hs, Ht, off, csr_tgt, (float2*)d_out, n, E);
}

// Round 16
// 252.541 us; speedup vs baseline: 5.9869x; 1.2976x over previous
//
#include <hip/hip_runtime.h>

#define DIM 128
#define HEADS 4
#define ODIM 32
#define LRELU 0.2f
#define PT 4096
#define HB_EDGES 4096

typedef unsigned int u32;
typedef unsigned short u16;

__device__ __forceinline__ u16 f2bf(float f) {
    union { u32 u; float f; } x; x.f = f;
    u32 u = x.u;
    u32 r = u + 0x7FFFu + ((u >> 16) & 1u);
    return (u16)(r >> 16);
}
__device__ __forceinline__ float blo(u32 b) {
    union { u32 u; float f; } x; x.u = b << 16; return x.f;
}
__device__ __forceinline__ float bhi(u32 b) {
    union { u32 u; float f; } x; x.u = b & 0xFFFF0000u; return x.f;
}

// ---------------------------------------------------------------------------
// 1) FUSED proj+scores: Hb = bf16x2(X@W); Hs/Ht via 8-lane shfl reduction
//    (lanes t&31 of a row-pair hold all 128 cols; head = (t&31)>>3).
// ---------------------------------------------------------------------------
__global__ __launch_bounds__(256) void proj_kernel(
    const float* __restrict__ X, const float* __restrict__ W,
    const float* __restrict__ AL, const float* __restrict__ AR,
    u32* __restrict__ Hb, float* __restrict__ Hs, float* __restrict__ Ht, int n)
{
    __shared__ alignas(16) float sW[64 * DIM];   // 32 KB
    __shared__ alignas(16) float sX[16][64];     // 4 KB
    __shared__ float sAL[DIM], sAR[DIM];         // 1 KB
    const int t = threadIdx.x;
    if (t < DIM) { sAL[t] = AL[t]; sAR[t] = AR[t]; }
    const int row0 = blockIdx.x * 16;
    const int c0 = (t & 31) * 4;
    const int r0 = (t >> 5) * 2;
    float a00=0,a01=0,a02=0,a03=0, a10=0,a11=0,a12=0,a13=0;

    for (int k0 = 0; k0 < DIM; k0 += 64) {
        #pragma unroll
        for (int i = 0; i < 8; ++i) {
            int idx = (i * 256 + t) * 4;
            *(float4*)&sW[idx] = *(const float4*)&W[k0 * DIM + idx];
        }
        {
            int idx = t * 4;
            int r = idx >> 6, k = idx & 63;
            int gr = row0 + r;
            float4 v = {0.f, 0.f, 0.f, 0.f};
            if (gr < n) v = *(const float4*)&X[(size_t)gr * DIM + k0 + k];
            *(float4*)&sX[r][k] = v;
        }
        __syncthreads();
        #pragma unroll 8
        for (int k = 0; k < 64; ++k) {
            float x0 = sX[r0][k], x1 = sX[r0 + 1][k];
            float4 wv = *(const float4*)&sW[k * DIM + c0];
            a00 += x0*wv.x; a01 += x0*wv.y; a02 += x0*wv.z; a03 += x0*wv.w;
            a10 += x1*wv.x; a11 += x1*wv.y; a12 += x1*wv.z; a13 += x1*wv.w;
        }
        __syncthreads();
    }
    int gr0 = row0 + r0;
    int d2 = c0 >> 1;
    if (gr0 < n) {
        uint2 p;
        p.x = ((u32)f2bf(a01) << 16) | (u32)f2bf(a00);
        p.y = ((u32)f2bf(a03) << 16) | (u32)f2bf(a02);
        *(uint2*)&Hb[(size_t)gr0 * 64 + d2] = p;
    }
    if (gr0 + 1 < n) {
        uint2 p;
        p.x = ((u32)f2bf(a11) << 16) | (u32)f2bf(a10);
        p.y = ((u32)f2bf(a13) << 16) | (u32)f2bf(a12);
        *(uint2*)&Hb[(size_t)(gr0 + 1) * 64 + d2] = p;
    }
    // fused scores: 4-col partial dots, reduce across the 8 lanes of the head
    float pL0 = a00*sAL[c0] + a01*sAL[c0+1] + a02*sAL[c0+2] + a03*sAL[c0+3];
    float pR0 = a00*sAR[c0] + a01*sAR[c0+1] + a02*sAR[c0+2] + a03*sAR[c0+3];
    float pL1 = a10*sAL[c0] + a11*sAL[c0+1] + a12*sAL[c0+2] + a13*sAL[c0+3];
    float pR1 = a10*sAR[c0] + a11*sAR[c0+1] + a12*sAR[c0+2] + a13*sAR[c0+3];
    #pragma unroll
    for (int m = 1; m <= 4; m <<= 1) {
        pL0 += __shfl_xor(pL0, m);
        pR0 += __shfl_xor(pR0, m);
        pL1 += __shfl_xor(pL1, m);
        pR1 += __shfl_xor(pR1, m);
    }
    if ((t & 7) == 0) {
        int h = (t & 31) >> 3;
        if (gr0 < n)     { Hs[gr0*HEADS + h] = pL0;     Ht[gr0*HEADS + h] = pR0; }
        if (gr0 + 1 < n) { Hs[(gr0+1)*HEADS + h] = pL1; Ht[(gr0+1)*HEADS + h] = pR1; }
    }
}

// ---------------------------------------------------------------------------
// 2) bucket histogram (196 bins = src>>8), private per-block rows, no atomics
//    on global, no memset needed.
// ---------------------------------------------------------------------------
__global__ __launch_bounds__(256) void hist196_kernel(
    const int* __restrict__ ei, int* __restrict__ gcnt, int E, int n)
{
    __shared__ int lc[256];
    int t = threadIdx.x;
    lc[t] = 0;
    __syncthreads();
    int base = blockIdx.x * HB_EDGES;
    for (int i = t; i < HB_EDGES; i += 256) {
        int e = base + i;
        if (e < E) {
            int src = ei[e];
            src = max(0, min(src, n - 1));
            atomicAdd(&lc[src >> 8], 1);
        }
    }
    __syncthreads();
    gcnt[blockIdx.x * 256 + t] = lc[t];
}

// ---------------------------------------------------------------------------
// 3) column-sum + scan (1 block): tsum, tpre (exclusive), bcur (=tpre copy)
// ---------------------------------------------------------------------------
__global__ __launch_bounds__(256) void scan196_kernel(
    const int* __restrict__ gcnt, int nb, int* __restrict__ tsum,
    int* __restrict__ tpre, int* __restrict__ bcur, int ntiles)
{
    __shared__ int s[256];
    int t = threadIdx.x;
    int sum = 0;
    #pragma unroll 4
    for (int r = 0; r < nb; ++r) sum += gcnt[r * 256 + t];
    s[t] = sum;
    __syncthreads();
    for (int ofs = 1; ofs < 256; ofs <<= 1) {
        int x = (t >= ofs) ? s[t - ofs] : 0;
        __syncthreads();
        s[t] += x;
        __syncthreads();
    }
    if (t < ntiles) {
        int ex = s[t] - sum;
        tsum[t] = sum;
        tpre[t] = ex;
        bcur[t] = ex;
    }
}

// ---------------------------------------------------------------------------
// 4) LDS-staged partition by bucket = src>>8; key = (src&255)<<17 | tgt
// ---------------------------------------------------------------------------
__global__ __launch_bounds__(256) void partition_kernel(
    const int* __restrict__ ei, int* __restrict__ bcur,
    u32* __restrict__ part, int E, int n)
{
    __shared__ u32 stage[PT];                  // 16 KB
    __shared__ int lcnt[256], loff[256], lcur[256], gbase[256];
    const int t = threadIdx.x;
    const int base = blockIdx.x * PT;
    lcnt[t] = 0;
    __syncthreads();

    u32 key[16];
    int bkt[16];
    #pragma unroll
    for (int i = 0; i < 16; ++i) {
        int e = base + i * 256 + t;
        bkt[i] = -1;
        key[i] = 0;
        if (e < E) {
            int src = ei[e];
            int tgt = ei[E + e];
            src = max(0, min(src, n - 1));
            tgt = max(0, min(tgt, n - 1));
            bkt[i] = src >> 8;
            key[i] = ((u32)(src & 255) << 17) | (u32)tgt;
            atomicAdd(&lcnt[bkt[i]], 1);
        }
    }
    __syncthreads();
    {
        int v = lcnt[t];
        loff[t] = v;
        __syncthreads();
        for (int ofs = 1; ofs < 256; ofs <<= 1) {
            int x = (t >= ofs) ? loff[t - ofs] : 0;
            __syncthreads();
            loff[t] += x;
            __syncthreads();
        }
        int incl = loff[t];
        __syncthreads();
        loff[t] = incl - v;
        lcur[t] = incl - v;
    }
    __syncthreads();
    #pragma unroll
    for (int i = 0; i < 16; ++i) {
        if (bkt[i] >= 0) {
            int p = atomicAdd(&lcur[bkt[i]], 1);
            stage[p] = key[i];
        }
    }
    {
        int c = lcnt[t];
        gbase[t] = (c > 0) ? atomicAdd(&bcur[t], c) : 0;
    }
    __syncthreads();
    int total = loff[255] + lcnt[255];
    for (int i = t; i < total; i += 256) {
        int lo = 0, hi = 255;
        while (lo < hi) {
            int mid = (lo + hi + 1) >> 1;
            if (loff[mid] <= i) lo = mid; else hi = mid - 1;
        }
        part[gbase[lo] + (i - loff[lo])] = stage[i];
    }
}

// ---------------------------------------------------------------------------
// 5) per-bucket counting sort: emits off[] for the bucket's 256 nodes AND
//    csr_tgt (LDS cursors, writes land in one ~32KB L2-local region).
// ---------------------------------------------------------------------------
__global__ __launch_bounds__(256) void csrfill_kernel(
    const u32* __restrict__ part, const int* __restrict__ tpre,
    const int* __restrict__ tsum, int* __restrict__ off,
    int* __restrict__ csr_tgt, int E, int n, int ntiles)
{
    __shared__ int lc[256], lo[256], lcur[256];
    const int b = blockIdx.x, t = threadIdx.x;
    const int base = tpre[b], cnt = tsum[b];
    lc[t] = 0;
    __syncthreads();
    for (int i = t; i < cnt; i += 256)
        atomicAdd(&lc[part[base + i] >> 17], 1);
    __syncthreads();
    {
        int v = lc[t];
        lo[t] = v;
        __syncthreads();
        for (int ofs = 1; ofs < 256; ofs <<= 1) {
            int x = (t >= ofs) ? lo[t - ofs] : 0;
            __syncthreads();
            lo[t] += x;
            __syncthreads();
        }
        int incl = lo[t];
        __syncthreads();
        lo[t] = incl - v;
        lcur[t] = incl - v;
    }
    __syncthreads();
    int node = b * 256 + t;
    if (node < n) off[node] = base + lo[t];
    if (b == ntiles - 1 && t == 0) off[n] = E;
    for (int i = t; i < cnt; i += 256) {
        u32 key = part[base + i];
        int p = atomicAdd(&lcur[key >> 17], 1);
        csr_tgt[base + p] = (int)(key & 0x1FFFFu);
    }
}

// ---------------------------------------------------------------------------
// 6) CSR-gather aggregation, bf16 payload, 8x unrolled gathers in flight.
// ---------------------------------------------------------------------------
__global__ __launch_bounds__(256) void agg_kernel(
    const u32* __restrict__ Hb, const float* __restrict__ Hs,
    const float* __restrict__ Ht, const int* __restrict__ off,
    const int* __restrict__ csr_tgt, float2* __restrict__ out, int n, int E)
{
    int node = (blockIdx.x * 256 + threadIdx.x) >> 6;
    int L = threadIdx.x & 63;
    if (node >= n) return;
    int lo = off[node], hi = off[node + 1];
    lo = max(0, min(lo, E));
    hi = max(lo, min(hi, E));
    int h = L >> 4;
    float hs = Hs[node * HEADS + h];
    float ax = 0.f, ay = 0.f, S = 0.f;

    int i = lo;
    for (; i + 8 <= hi; i += 8) {
        int tt[8];
        #pragma unroll
        for (int j = 0; j < 8; ++j) tt[j] = csr_tgt[i + j];
        float ee[8];
        #pragma unroll
        for (int j = 0; j < 8; ++j) ee[j] = Ht[tt[j] * HEADS + h];
        u32 bb[8];
        #pragma unroll
        for (int j = 0; j < 8; ++j) bb[j] = Hb[(size_t)tt[j] * 64 + L];
        #pragma unroll
        for (int j = 0; j < 8; ++j) {
            float e = hs + ee[j];
            float w = __expf(fminf(e > 0.f ? e : LRELU * e, 30.f));
            ax += w * blo(bb[j]);
            ay += w * bhi(bb[j]);
            S += w;
        }
    }
    for (; i < hi; ++i) {
        int tgt = csr_tgt[i];
        float e = hs + Ht[tgt * HEADS + h];
        float w = __expf(fminf(e > 0.f ? e : LRELU * e, 30.f));
        u32 b = Hb[(size_t)tgt * 64 + L];
        ax += w * blo(b);
        ay += w * bhi(b);
        S += w;
    }
    float inv = 1.f / (S + 1e-8f);
    float ox = ax * inv, oy = ay * inv;
    ox = ox > 0.f ? ox : (__expf(ox) - 1.f);
    oy = oy > 0.f ? oy : (__expf(oy) - 1.f);
    out[(size_t)node * 64 + L] = {ox, oy};
}

// ---------------------------------------------------------------------------
extern "C" void kernel_launch(void* const* d_in, const int* in_sizes, int n_in,
                              void* d_out, int out_size, void* d_ws, size_t ws_size,
                              hipStream_t stream) {
    const float* X  = (const float*)d_in[0];   // fp32
    const int*   EI = (const int*)d_in[1];     // int32[2E] block layout
    const float* W  = (const float*)d_in[2];   // fp32 row-major
    const float* AL = (const float*)d_in[3];
    const float* AR = (const float*)d_in[4];
    const int n = in_sizes[0] / DIM;      // 50000
    const int E = in_sizes[1] / 2;        // 1600000
    const int ntiles = (n + 255) / 256;   // 196 buckets
    const int nhb = (E + HB_EDGES - 1) / HB_EDGES;   // 391

    char* ws = (char*)d_ws;
    size_t o = 0;
    auto alloc = [&](size_t bytes) -> void* {
        o = (o + 255) & ~(size_t)255;
        void* p = ws + o;
        o += bytes;
        return p;
    };
    // total ~28.5 MB
    int*   gcnt    = (int*)alloc((size_t)nhb * 256 * 4);   // 400 KB
    int*   tsum    = (int*)alloc(256 * 4);
    int*   tpre    = (int*)alloc(256 * 4);
    int*   bcur    = (int*)alloc(256 * 4);
    int*   off     = (int*)alloc((size_t)(n + 1) * 4);
    float* Hs      = (float*)alloc((size_t)n * HEADS * 4);
    float* Ht      = (float*)alloc((size_t)n * HEADS * 4);
    int*   csr_tgt = (int*)alloc((size_t)E * 4);
    u32*   part    = (u32*)alloc((size_t)E * 4);
    u32*   Hb      = (u32*)alloc((size_t)n * 64 * 4);

    proj_kernel<<<(n + 15) / 16, 256, 0, stream>>>(X, W, AL, AR, Hb, Hs, Ht, n);
    hist196_kernel<<<nhb, 256, 0, stream>>>(EI, gcnt, E, n);
    scan196_kernel<<<1, 256, 0, stream>>>(gcnt, nhb, tsum, tpre, bcur, ntiles);
    partition_kernel<<<(E + PT - 1) / PT, 256, 0, stream>>>(EI, bcur, part, E, n);
    csrfill_kernel<<<ntiles, 256, 0, stream>>>(part, tpre, tsum, off, csr_tgt, E, n, ntiles);
    agg_kernel<<<(n + 3) / 4, 256, 0, stream>>>(
        Hb, Hs, Ht, off, csr_tgt, (float2*)d_out, n, E);
}

// Round 17
// 240.066 us; speedup vs baseline: 6.2981x; 1.0520x over previous
//
#include <hip/hip_runtime.h>

#define DIM 128
#define HEADS 4
#define ODIM 32
#define LRELU 0.2f
#define PT 4096
#define HB_EDGES 4096

typedef unsigned int u32;
typedef unsigned short u16;
typedef unsigned char u8;

__device__ __forceinline__ u16 f2bf(float f) {
    union { u32 u; float f; } x; x.f = f;
    u32 u = x.u;
    u32 r = u + 0x7FFFu + ((u >> 16) & 1u);
    return (u16)(r >> 16);
}
__device__ __forceinline__ float blo(u32 b) {
    union { u32 u; float f; } x; x.u = b << 16; return x.f;
}
__device__ __forceinline__ float bhi(u32 b) {
    union { u32 u; float f; } x; x.u = b & 0xFFFF0000u; return x.f;
}

// ---------------------------------------------------------------------------
// 1) FUSED proj+scores: Hb = bf16x2(X@W); Hs/Ht via 8-lane shfl reduction
// ---------------------------------------------------------------------------
__global__ __launch_bounds__(256) void proj_kernel(
    const float* __restrict__ X, const float* __restrict__ W,
    const float* __restrict__ AL, const float* __restrict__ AR,
    u32* __restrict__ Hb, float* __restrict__ Hs, float* __restrict__ Ht, int n)
{
    __shared__ alignas(16) float sW[64 * DIM];   // 32 KB
    __shared__ alignas(16) float sX[16][64];     // 4 KB
    __shared__ float sAL[DIM], sAR[DIM];         // 1 KB
    const int t = threadIdx.x;
    if (t < DIM) { sAL[t] = AL[t]; sAR[t] = AR[t]; }
    const int row0 = blockIdx.x * 16;
    const int c0 = (t & 31) * 4;
    const int r0 = (t >> 5) * 2;
    float a00=0,a01=0,a02=0,a03=0, a10=0,a11=0,a12=0,a13=0;

    for (int k0 = 0; k0 < DIM; k0 += 64) {
        #pragma unroll
        for (int i = 0; i < 8; ++i) {
            int idx = (i * 256 + t) * 4;
            *(float4*)&sW[idx] = *(const float4*)&W[k0 * DIM + idx];
        }
        {
            int idx = t * 4;
            int r = idx >> 6, k = idx & 63;
            int gr = row0 + r;
            float4 v = {0.f, 0.f, 0.f, 0.f};
            if (gr < n) v = *(const float4*)&X[(size_t)gr * DIM + k0 + k];
            *(float4*)&sX[r][k] = v;
        }
        __syncthreads();
        #pragma unroll 8
        for (int k = 0; k < 64; ++k) {
            float x0 = sX[r0][k], x1 = sX[r0 + 1][k];
            float4 wv = *(const float4*)&sW[k * DIM + c0];
            a00 += x0*wv.x; a01 += x0*wv.y; a02 += x0*wv.z; a03 += x0*wv.w;
            a10 += x1*wv.x; a11 += x1*wv.y; a12 += x1*wv.z; a13 += x1*wv.w;
        }
        __syncthreads();
    }
    int gr0 = row0 + r0;
    int d2 = c0 >> 1;
    if (gr0 < n) {
        uint2 p;
        p.x = ((u32)f2bf(a01) << 16) | (u32)f2bf(a00);
        p.y = ((u32)f2bf(a03) << 16) | (u32)f2bf(a02);
        *(uint2*)&Hb[(size_t)gr0 * 64 + d2] = p;
    }
    if (gr0 + 1 < n) {
        uint2 p;
        p.x = ((u32)f2bf(a11) << 16) | (u32)f2bf(a10);
        p.y = ((u32)f2bf(a13) << 16) | (u32)f2bf(a12);
        *(uint2*)&Hb[(size_t)(gr0 + 1) * 64 + d2] = p;
    }
    float pL0 = a00*sAL[c0] + a01*sAL[c0+1] + a02*sAL[c0+2] + a03*sAL[c0+3];
    float pR0 = a00*sAR[c0] + a01*sAR[c0+1] + a02*sAR[c0+2] + a03*sAR[c0+3];
    float pL1 = a10*sAL[c0] + a11*sAL[c0+1] + a12*sAL[c0+2] + a13*sAL[c0+3];
    float pR1 = a10*sAR[c0] + a11*sAR[c0+1] + a12*sAR[c0+2] + a13*sAR[c0+3];
    #pragma unroll
    for (int m = 1; m <= 4; m <<= 1) {
        pL0 += __shfl_xor(pL0, m);
        pR0 += __shfl_xor(pR0, m);
        pL1 += __shfl_xor(pL1, m);
        pR1 += __shfl_xor(pR1, m);
    }
    if ((t & 7) == 0) {
        int h = (t & 31) >> 3;
        if (gr0 < n)     { Hs[gr0*HEADS + h] = pL0;     Ht[gr0*HEADS + h] = pR0; }
        if (gr0 + 1 < n) { Hs[(gr0+1)*HEADS + h] = pL1; Ht[(gr0+1)*HEADS + h] = pR1; }
    }
}

// ---------------------------------------------------------------------------
// 2) bucket histogram (196 bins = src>>8), per-block private LDS rows
// ---------------------------------------------------------------------------
__global__ __launch_bounds__(256) void hist196_kernel(
    const int* __restrict__ ei, int* __restrict__ gcnt, int E, int n)
{
    __shared__ int lc[256];
    int t = threadIdx.x;
    lc[t] = 0;
    __syncthreads();
    int base = blockIdx.x * HB_EDGES;
    for (int i = t; i < HB_EDGES; i += 256) {
        int e = base + i;
        if (e < E) {
            int src = ei[e];
            src = max(0, min(src, n - 1));
            atomicAdd(&lc[src >> 8], 1);
        }
    }
    __syncthreads();
    gcnt[blockIdx.x * 256 + t] = lc[t];
}

// ---------------------------------------------------------------------------
// 3) column-sum + scan (1 block): tsum, tpre (exclusive), bcur (copy)
// ---------------------------------------------------------------------------
__global__ __launch_bounds__(256) void scan196_kernel(
    const int* __restrict__ gcnt, int nb, int* __restrict__ tsum,
    int* __restrict__ tpre, int* __restrict__ bcur, int ntiles)
{
    __shared__ int s[256];
    int t = threadIdx.x;
    int sum = 0;
    #pragma unroll 4
    for (int r = 0; r < nb; ++r) sum += gcnt[r * 256 + t];
    s[t] = sum;
    __syncthreads();
    for (int ofs = 1; ofs < 256; ofs <<= 1) {
        int x = (t >= ofs) ? s[t - ofs] : 0;
        __syncthreads();
        s[t] += x;
        __syncthreads();
    }
    if (t < ntiles) {
        int ex = s[t] - sum;
        tsum[t] = sum;
        tpre[t] = ex;
        bcur[t] = ex;
    }
}

// ---------------------------------------------------------------------------
// 4) LDS-staged partition by bucket = src>>8; key = (src&255)<<17 | tgt.
//    sbkt[] records each LDS slot's bucket -> direct flush (no binary search).
// ---------------------------------------------------------------------------
__global__ __launch_bounds__(256) void partition_kernel(
    const int* __restrict__ ei, int* __restrict__ bcur,
    u32* __restrict__ part, int E, int n)
{
    __shared__ u32 stage[PT];                  // 16 KB
    __shared__ u8  sbkt[PT];                   // 4 KB
    __shared__ int lcnt[256], loff[256], lcur[256], gbase[256];
    const int t = threadIdx.x;
    const int base = blockIdx.x * PT;
    lcnt[t] = 0;
    __syncthreads();

    u32 key[16];
    int bkt[16];
    #pragma unroll
    for (int i = 0; i < 16; ++i) {
        int e = base + i * 256 + t;
        bkt[i] = -1;
        key[i] = 0;
        if (e < E) {
            int src = ei[e];
            int tgt = ei[E + e];
            src = max(0, min(src, n - 1));
            tgt = max(0, min(tgt, n - 1));
            bkt[i] = src >> 8;
            key[i] = ((u32)(src & 255) << 17) | (u32)tgt;
            atomicAdd(&lcnt[bkt[i]], 1);
        }
    }
    __syncthreads();
    {
        int v = lcnt[t];
        loff[t] = v;
        __syncthreads();
        for (int ofs = 1; ofs < 256; ofs <<= 1) {
            int x = (t >= ofs) ? loff[t - ofs] : 0;
            __syncthreads();
            loff[t] += x;
            __syncthreads();
        }
        int incl = loff[t];
        __syncthreads();
        loff[t] = incl - v;
        lcur[t] = incl - v;
    }
    __syncthreads();
    #pragma unroll
    for (int i = 0; i < 16; ++i) {
        if (bkt[i] >= 0) {
            int p = atomicAdd(&lcur[bkt[i]], 1);
            stage[p] = key[i];
            sbkt[p] = (u8)bkt[i];
        }
    }
    {
        int c = lcnt[t];
        gbase[t] = (c > 0) ? atomicAdd(&bcur[t], c) : 0;
    }
    __syncthreads();
    int total = loff[255] + lcnt[255];
    for (int i = t; i < total; i += 256) {
        int b = sbkt[i];
        part[gbase[b] + (i - loff[b])] = stage[i];
    }
}

// ---------------------------------------------------------------------------
// 5) per-bucket counting sort -> off[] + csr_tgt (L2-local writes)
// ---------------------------------------------------------------------------
__global__ __launch_bounds__(256) void csrfill_kernel(
    const u32* __restrict__ part, const int* __restrict__ tpre,
    const int* __restrict__ tsum, int* __restrict__ off,
    int* __restrict__ csr_tgt, int E, int n, int ntiles)
{
    __shared__ int lc[256], lo[256], lcur[256];
    const int b = blockIdx.x, t = threadIdx.x;
    const int base = tpre[b], cnt = tsum[b];
    lc[t] = 0;
    __syncthreads();
    for (int i = t; i < cnt; i += 256)
        atomicAdd(&lc[part[base + i] >> 17], 1);
    __syncthreads();
    {
        int v = lc[t];
        lo[t] = v;
        __syncthreads();
        for (int ofs = 1; ofs < 256; ofs <<= 1) {
            int x = (t >= ofs) ? lo[t - ofs] : 0;
            __syncthreads();
            lo[t] += x;
            __syncthreads();
        }
        int incl = lo[t];
        __syncthreads();
        lo[t] = incl - v;
        lcur[t] = incl - v;
    }
    __syncthreads();
    int node = b * 256 + t;
    if (node < n) off[node] = base + lo[t];
    if (b == ntiles - 1 && t == 0) off[n] = E;
    for (int i = t; i < cnt; i += 256) {
        u32 key = part[base + i];
        int p = atomicAdd(&lcur[key >> 17], 1);
        csr_tgt[base + p] = (int)(key & 0x1FFFFu);
    }
}

// ---------------------------------------------------------------------------
// 6) CSR-gather aggregation. w computed ONCE per (edge,head) on lanes 0-31
//    and shfl-broadcast (was 16x redundant). 32-bit Hb addressing.
// ---------------------------------------------------------------------------
__global__ __launch_bounds__(256) void agg_kernel(
    const u32* __restrict__ Hb, const float* __restrict__ Hs,
    const float* __restrict__ Ht, const int* __restrict__ off,
    const int* __restrict__ csr_tgt, float2* __restrict__ out, int n, int E)
{
    int node = (blockIdx.x * 256 + threadIdx.x) >> 6;
    int L = threadIdx.x & 63;
    if (node >= n) return;
    int lo = off[node], hi = off[node + 1];
    lo = max(0, min(lo, E));
    hi = max(lo, min(hi, E));
    const int h = L >> 4;                 // own accumulate head
    const int eSel = (L & 31) >> 2;       // compute-duty: edge index in batch
    const int hSel = L & 3;               // compute-duty: head
    float4 hs4 = *(const float4*)&Hs[node * HEADS];
    float hsC = hSel == 0 ? hs4.x : hSel == 1 ? hs4.y : hSel == 2 ? hs4.z : hs4.w;
    float hsO = h == 0 ? hs4.x : h == 1 ? hs4.y : h == 2 ? hs4.z : hs4.w;
    float ax = 0.f, ay = 0.f, S = 0.f;

    int i = lo;
    for (; i + 8 <= hi; i += 8) {
        int tt[8];
        #pragma unroll
        for (int j = 0; j < 8; ++j) tt[j] = csr_tgt[i + j];
        // compute-duty: w for (edge eSel, head hSel) — one chain per lane
        int tsel = csr_tgt[i + eSel];
        float e = hsC + Ht[tsel * HEADS + hSel];
        float w = __expf(fminf(e > 0.f ? e : LRELU * e, 30.f));
        u32 bb[8];
        #pragma unroll
        for (int j = 0; j < 8; ++j) bb[j] = Hb[tt[j] * 64 + L];
        #pragma unroll
        for (int j = 0; j < 8; ++j) {
            float wj = __shfl(w, (j << 2) | h);
            ax += wj * blo(bb[j]);
            ay += wj * bhi(bb[j]);
            S += wj;
        }
    }
    for (; i < hi; ++i) {
        int tgt = csr_tgt[i];
        float e = hsO + Ht[tgt * HEADS + h];
        float w = __expf(fminf(e > 0.f ? e : LRELU * e, 30.f));
        u32 b = Hb[tgt * 64 + L];
        ax += w * blo(b);
        ay += w * bhi(b);
        S += w;
    }
    float inv = 1.f / (S + 1e-8f);
    float ox = ax * inv, oy = ay * inv;
    ox = ox > 0.f ? ox : (__expf(ox) - 1.f);
    oy = oy > 0.f ? oy : (__expf(oy) - 1.f);
    out[(size_t)node * 64 + L] = {ox, oy};
}

// ---------------------------------------------------------------------------
extern "C" void kernel_launch(void* const* d_in, const int* in_sizes, int n_in,
                              void* d_out, int out_size, void* d_ws, size_t ws_size,
                              hipStream_t stream) {
    const float* X  = (const float*)d_in[0];   // fp32
    const int*   EI = (const int*)d_in[1];     // int32[2E] block layout
    const float* W  = (const float*)d_in[2];   // fp32 row-major
    const float* AL = (const float*)d_in[3];
    const float* AR = (const float*)d_in[4];
    const int n = in_sizes[0] / DIM;      // 50000
    const int E = in_sizes[1] / 2;        // 1600000
    const int ntiles = (n + 255) / 256;   // 196 buckets
    const int nhb = (E + HB_EDGES - 1) / HB_EDGES;   // 391

    char* ws = (char*)d_ws;
    size_t o = 0;
    auto alloc = [&](size_t bytes) -> void* {
        o = (o + 255) & ~(size_t)255;
        void* p = ws + o;
        o += bytes;
        return p;
    };
    int*   gcnt    = (int*)alloc((size_t)nhb * 256 * 4);
    int*   tsum    = (int*)alloc(256 * 4);
    int*   tpre    = (int*)alloc(256 * 4);
    int*   bcur    = (int*)alloc(256 * 4);
    int*   off     = (int*)alloc((size_t)(n + 1) * 4);
    float* Hs      = (float*)alloc((size_t)n * HEADS * 4);
    float* Ht      = (float*)alloc((size_t)n * HEADS * 4);
    int*   csr_tgt = (int*)alloc((size_t)E * 4);
    u32*   part    = (u32*)alloc((size_t)E * 4);
    u32*   Hb      = (u32*)alloc((size_t)n * 64 * 4);

    proj_kernel<<<(n + 15) / 16, 256, 0, stream>>>(X, W, AL, AR, Hb, Hs, Ht, n);
    hist196_kernel<<<nhb, 256, 0, stream>>>(EI, gcnt, E, n);
    scan196_kernel<<<1, 256, 0, stream>>>(gcnt, nhb, tsum, tpre, bcur, ntiles);
    partition_kernel<<<(E + PT - 1) / PT, 256, 0, stream>>>(EI, bcur, part, E, n);
    csrfill_kernel<<<ntiles, 256, 0, stream>>>(part, tpre, tsum, off, csr_tgt, E, n, ntiles);
    agg_kernel<<<(n + 3) / 4, 256, 0, stream>>>(
        Hb, Hs, Ht, off, csr_tgt, (float2*)d_out, n, E);
}

// Round 18
// 210.702 us; speedup vs baseline: 7.1758x; 1.1394x over previous
//
#include <hip/hip_runtime.h>

#define DIM 128
#define HEADS 4
#define ODIM 32
#define LRELU 0.2f
#define PT 4096
#define CAP 9216

typedef unsigned int u32;
typedef unsigned short u16;
typedef unsigned char u8;

typedef __attribute__((ext_vector_type(8))) short bf16x8;
typedef __attribute__((ext_vector_type(4))) float f32x4;

__device__ __forceinline__ u16 f2bf(float f) {
    union { u32 u; float f; } x; x.f = f;
    u32 u = x.u;
    u32 r = u + 0x7FFFu + ((u >> 16) & 1u);
    return (u16)(r >> 16);
}
__device__ __forceinline__ float blo(u32 b) {
    union { u32 u; float f; } x; x.u = b << 16; return x.f;
}
__device__ __forceinline__ float bhi(u32 b) {
    union { u32 u; float f; } x; x.u = b & 0xFFFF0000u; return x.f;
}

// ---------------------------------------------------------------------------
// 1) MFMA proj + fused scores. 64 rows/block (4 waves x 16), bf16 inputs,
//    fp32 accum. LDS rows padded to 136 bf16 for conflict-free ds_read_b128.
//    Block 0 also initializes the partition bucket cursors.
// ---------------------------------------------------------------------------
__global__ __launch_bounds__(256) void proj_kernel(
    const float* __restrict__ X, const float* __restrict__ W,
    const float* __restrict__ AL, const float* __restrict__ AR,
    u32* __restrict__ Hb, float* __restrict__ Hs, float* __restrict__ Ht,
    int* __restrict__ bcur, int n)
{
    __shared__ alignas(16) u16 sWt[128 * 136];   // 34816 B; reused as sH (fp32 64x132)
    __shared__ alignas(16) u16 sXb[64 * 136];    // 17408 B
    __shared__ float sAL[DIM], sAR[DIM];         // 1 KB
    const int t = threadIdx.x;
    if (blockIdx.x == 0) bcur[t] = t * CAP;      // partition cursor init (fused)
    if (t < DIM) { sAL[t] = AL[t]; sAR[t] = AR[t]; }
    const int row0 = blockIdx.x * 64;

    // stage W transposed: sWt[n][k] (bf16), coalesced fp32 reads
    #pragma unroll
    for (int i = 0; i < 16; ++i) {
        int idx = (i * 256 + t) * 4;
        int k = idx >> 7, nn = idx & 127;
        float4 v = *(const float4*)&W[idx];
        sWt[(nn + 0) * 136 + k] = f2bf(v.x);
        sWt[(nn + 1) * 136 + k] = f2bf(v.y);
        sWt[(nn + 2) * 136 + k] = f2bf(v.z);
        sWt[(nn + 3) * 136 + k] = f2bf(v.w);
    }
    // stage X rows: sXb[r][k] (bf16)
    #pragma unroll
    for (int i = 0; i < 8; ++i) {
        int idx = (i * 256 + t) * 4;
        int r = idx >> 7, k = idx & 127;
        int gr = row0 + r;
        float4 v = {0.f, 0.f, 0.f, 0.f};
        if (gr < n) v = *(const float4*)&X[(size_t)gr * DIM + k];
        u16* p = &sXb[r * 136 + k];
        p[0] = f2bf(v.x); p[1] = f2bf(v.y); p[2] = f2bf(v.z); p[3] = f2bf(v.w);
    }
    __syncthreads();

    const int w = t >> 6;
    const int lane = t & 63;
    const int quad = lane >> 4;
    const int nIdx = lane & 15;
    f32x4 acc[8];
    #pragma unroll
    for (int c = 0; c < 8; ++c) acc[c] = (f32x4){0.f, 0.f, 0.f, 0.f};

    const u16* aBase = &sXb[(w * 16 + nIdx) * 136 + quad * 8];
    #pragma unroll
    for (int kq = 0; kq < 4; ++kq) {
        bf16x8 a = *(const bf16x8*)&aBase[kq * 32];
        #pragma unroll
        for (int c = 0; c < 8; ++c) {
            bf16x8 b = *(const bf16x8*)&sWt[(c * 16 + nIdx) * 136 + quad * 8 + kq * 32];
            acc[c] = __builtin_amdgcn_mfma_f32_16x16x32_bf16(a, b, acc[c], 0, 0, 0);
        }
    }
    __syncthreads();                      // sWt/sXb reads done; reuse sWt as sH
    float* sH = (float*)sWt;              // 64 x 132 fp32
    #pragma unroll
    for (int c = 0; c < 8; ++c)
        #pragma unroll
        for (int r = 0; r < 4; ++r)
            sH[(w * 16 + quad * 4 + r) * 132 + c * 16 + nIdx] = acc[c][r];
    __syncthreads();

    // Hb: pack dim pairs -> bf16x2, coalesced
    #pragma unroll
    for (int i = 0; i < 16; ++i) {
        int idx = i * 256 + t;            // 4096 = 64 rows x 64 pairs
        int r = idx >> 6, d2 = idx & 63;
        int gr = row0 + r;
        if (gr < n) {
            float2 hv = *(const float2*)&sH[r * 132 + 2 * d2];
            Hb[(size_t)gr * 64 + d2] = ((u32)f2bf(hv.y) << 16) | (u32)f2bf(hv.x);
        }
    }
    // scores: thread (row = t>>2, h = t&3)
    {
        int r = t >> 2, h = t & 3;
        float s = 0.f, s2 = 0.f;
        #pragma unroll
        for (int q = 0; q < ODIM; q += 4) {
            float4 hv = *(const float4*)&sH[r * 132 + h * ODIM + q];
            s  += hv.x*sAL[h*ODIM+q] + hv.y*sAL[h*ODIM+q+1] + hv.z*sAL[h*ODIM+q+2] + hv.w*sAL[h*ODIM+q+3];
            s2 += hv.x*sAR[h*ODIM+q] + hv.y*sAR[h*ODIM+q+1] + hv.z*sAR[h*ODIM+q+2] + hv.w*sAR[h*ODIM+q+3];
        }
        int gr = row0 + r;
        if (gr < n) { Hs[gr * HEADS + h] = s; Ht[gr * HEADS + h] = s2; }
    }
}

// ---------------------------------------------------------------------------
// 2) LDS-staged partition into FIXED per-bucket regions [b*CAP, (b+1)*CAP).
//    bucket = src>>8; key = (src&255)<<17 | tgt. sbkt[] -> direct flush.
// ---------------------------------------------------------------------------
__global__ __launch_bounds__(256) void partition_kernel(
    const int* __restrict__ ei, int* __restrict__ bcur,
    u32* __restrict__ part, int E, int n)
{
    __shared__ u32 stage[PT];                  // 16 KB
    __shared__ u8  sbkt[PT];                   // 4 KB
    __shared__ int lcnt[256], loff[256], lcur[256], gbase[256];
    const int t = threadIdx.x;
    const int base = blockIdx.x * PT;
    lcnt[t] = 0;
    __syncthreads();

    u32 key[16];
    int bkt[16];
    #pragma unroll
    for (int i = 0; i < 16; ++i) {
        int e = base + i * 256 + t;
        bkt[i] = -1;
        key[i] = 0;
        if (e < E) {
            int src = ei[e];
            int tgt = ei[E + e];
            src = max(0, min(src, n - 1));
            tgt = max(0, min(tgt, n - 1));
            bkt[i] = src >> 8;
            key[i] = ((u32)(src & 255) << 17) | (u32)tgt;
            atomicAdd(&lcnt[bkt[i]], 1);
        }
    }
    __syncthreads();
    {
        int v = lcnt[t];
        loff[t] = v;
        __syncthreads();
        for (int ofs = 1; ofs < 256; ofs <<= 1) {
            int x = (t >= ofs) ? loff[t - ofs] : 0;
            __syncthreads();
            loff[t] += x;
            __syncthreads();
        }
        int incl = loff[t];
        __syncthreads();
        loff[t] = incl - v;
        lcur[t] = incl - v;
    }
    __syncthreads();
    #pragma unroll
    for (int i = 0; i < 16; ++i) {
        if (bkt[i] >= 0) {
            int p = atomicAdd(&lcur[bkt[i]], 1);
            stage[p] = key[i];
            sbkt[p] = (u8)bkt[i];
        }
    }
    {
        int c = lcnt[t];
        gbase[t] = (c > 0) ? atomicAdd(&bcur[t], c) : 0;
    }
    __syncthreads();
    int total = loff[255] + lcnt[255];
    for (int i = t; i < total; i += 256) {
        int b = sbkt[i];
        int dst = gbase[b] + (i - loff[b]);
        if (dst < (b + 1) * CAP) part[dst] = stage[i];   // overflow guard (~never)
    }
}

// ---------------------------------------------------------------------------
// 3) bucket counts from cursors -> tsum + exclusive prefix tpre (1 block)
// ---------------------------------------------------------------------------
__global__ __launch_bounds__(256) void scanB_kernel(
    const int* __restrict__ bcur, int* __restrict__ tsum,
    int* __restrict__ tpre, int ntiles)
{
    __shared__ int s[256];
    int t = threadIdx.x;
    int cnt = (t < ntiles) ? (bcur[t] - t * CAP) : 0;
    cnt = max(0, min(cnt, CAP));
    s[t] = cnt;
    __syncthreads();
    for (int ofs = 1; ofs < 256; ofs <<= 1) {
        int x = (t >= ofs) ? s[t - ofs] : 0;
        __syncthreads();
        s[t] += x;
        __syncthreads();
    }
    if (t < ntiles) {
        tsum[t] = cnt;
        tpre[t] = s[t] - cnt;
    }
}

// ---------------------------------------------------------------------------
// 4) per-bucket counting sort -> off[] + csr_tgt (L2-local writes)
// ---------------------------------------------------------------------------
__global__ __launch_bounds__(256) void csrfill_kernel(
    const u32* __restrict__ part, const int* __restrict__ tpre,
    const int* __restrict__ tsum, int* __restrict__ off,
    int* __restrict__ csr_tgt, int E, int n, int ntiles)
{
    __shared__ int lc[256], lo[256], lcur[256];
    const int b = blockIdx.x, t = threadIdx.x;
    const int pbase = b * CAP;
    const int base = tpre[b], cnt = tsum[b];
    lc[t] = 0;
    __syncthreads();
    for (int i = t; i < cnt; i += 256)
        atomicAdd(&lc[part[pbase + i] >> 17], 1);
    __syncthreads();
    {
        int v = lc[t];
        lo[t] = v;
        __syncthreads();
        for (int ofs = 1; ofs < 256; ofs <<= 1) {
            int x = (t >= ofs) ? lo[t - ofs] : 0;
            __syncthreads();
            lo[t] += x;
            __syncthreads();
        }
        int incl = lo[t];
        __syncthreads();
        lo[t] = incl - v;
        lcur[t] = incl - v;
    }
    __syncthreads();
    int node = b * 256 + t;
    if (node < n) off[node] = base + lo[t];
    if (b == ntiles - 1 && t == 0) off[n] = base + cnt;
    for (int i = t; i < cnt; i += 256) {
        u32 key = part[pbase + i];
        int p = atomicAdd(&lcur[key >> 17], 1);
        csr_tgt[base + p] = (int)(key & 0x1FFFFu);
    }
}

// ---------------------------------------------------------------------------
// 5) CSR-gather aggregation (unchanged from R17): shfl w-dedup, 8x batches.
// ---------------------------------------------------------------------------
__global__ __launch_bounds__(256) void agg_kernel(
    const u32* __restrict__ Hb, const float* __restrict__ Hs,
    const float* __restrict__ Ht, const int* __restrict__ off,
    const int* __restrict__ csr_tgt, float2* __restrict__ out, int n, int E)
{
    int node = (blockIdx.x * 256 + threadIdx.x) >> 6;
    int L = threadIdx.x & 63;
    if (node >= n) return;
    int lo = off[node], hi = off[node + 1];
    lo = max(0, min(lo, E));
    hi = max(lo, min(hi, E));
    const int h = L >> 4;
    const int eSel = (L & 31) >> 2;
    const int hSel = L & 3;
    float4 hs4 = *(const float4*)&Hs[node * HEADS];
    float hsC = hSel == 0 ? hs4.x : hSel == 1 ? hs4.y : hSel == 2 ? hs4.z : hs4.w;
    float hsO = h == 0 ? hs4.x : h == 1 ? hs4.y : h == 2 ? hs4.z : hs4.w;
    float ax = 0.f, ay = 0.f, S = 0.f;

    int i = lo;
    for (; i + 8 <= hi; i += 8) {
        int tt[8];
        #pragma unroll
        for (int j = 0; j < 8; ++j) tt[j] = csr_tgt[i + j];
        int tsel = csr_tgt[i + eSel];
        float e = hsC + Ht[tsel * HEADS + hSel];
        float w = __expf(fminf(e > 0.f ? e : LRELU * e, 30.f));
        u32 bb[8];
        #pragma unroll
        for (int j = 0; j < 8; ++j) bb[j] = Hb[tt[j] * 64 + L];
        #pragma unroll
        for (int j = 0; j < 8; ++j) {
            float wj = __shfl(w, (j << 2) | h);
            ax += wj * blo(bb[j]);
            ay += wj * bhi(bb[j]);
            S += wj;
        }
    }
    for (; i < hi; ++i) {
        int tgt = csr_tgt[i];
        float e = hsO + Ht[tgt * HEADS + h];
        float w = __expf(fminf(e > 0.f ? e : LRELU * e, 30.f));
        u32 b = Hb[tgt * 64 + L];
        ax += w * blo(b);
        ay += w * bhi(b);
        S += w;
    }
    float inv = 1.f / (S + 1e-8f);
    float ox = ax * inv, oy = ay * inv;
    ox = ox > 0.f ? ox : (__expf(ox) - 1.f);
    oy = oy > 0.f ? oy : (__expf(oy) - 1.f);
    out[(size_t)node * 64 + L] = {ox, oy};
}

// ---------------------------------------------------------------------------
extern "C" void kernel_launch(void* const* d_in, const int* in_sizes, int n_in,
                              void* d_out, int out_size, void* d_ws, size_t ws_size,
                              hipStream_t stream) {
    const float* X  = (const float*)d_in[0];   // fp32
    const int*   EI = (const int*)d_in[1];     // int32[2E] block layout
    const float* W  = (const float*)d_in[2];   // fp32 row-major
    const float* AL = (const float*)d_in[3];
    const float* AR = (const float*)d_in[4];
    const int n = in_sizes[0] / DIM;      // 50000
    const int E = in_sizes[1] / 2;        // 1600000
    const int ntiles = (n + 255) / 256;   // 196 buckets

    char* ws = (char*)d_ws;
    size_t o = 0;
    auto alloc = [&](size_t bytes) -> void* {
        o = (o + 255) & ~(size_t)255;
        void* p = ws + o;
        o += bytes;
        return p;
    };
    int*   bcur    = (int*)alloc(256 * 4);
    int*   tsum    = (int*)alloc(256 * 4);
    int*   tpre    = (int*)alloc(256 * 4);
    int*   off     = (int*)alloc((size_t)(n + 1) * 4);
    float* Hs      = (float*)alloc((size_t)n * HEADS * 4);
    float* Ht      = (float*)alloc((size_t)n * HEADS * 4);
    int*   csr_tgt = (int*)alloc((size_t)E * 4);
    u32*   part    = (u32*)alloc((size_t)ntiles * CAP * 4);   // 7.2 MB
    u32*   Hb      = (u32*)alloc((size_t)n * 64 * 4);

    proj_kernel<<<(n + 63) / 64, 256, 0, stream>>>(X, W, AL, AR, Hb, Hs, Ht, bcur, n);
    partition_kernel<<<(E + PT - 1) / PT, 256, 0, stream>>>(EI, bcur, part, E, n);
    scanB_kernel<<<1, 256, 0, stream>>>(bcur, tsum, tpre, ntiles);
    csrfill_kernel<<<ntiles, 256, 0, stream>>>(part, tpre, tsum, off, csr_tgt, E, n, ntiles);
    agg_kernel<<<(n + 3) / 4, 256, 0, stream>>>(
        Hb, Hs, Ht, off, csr_tgt, (float2*)d_out, n, E);
}

// Round 19
// 208.329 us; speedup vs baseline: 7.2575x; 1.0114x over previous
//
#include <hip/hip_runtime.h>

#define DIM 128
#define HEADS 4
#define ODIM 32
#define LRELU 0.2f
#define PT 4096
#define CAP 9216

typedef unsigned int u32;
typedef unsigned short u16;
typedef unsigned char u8;

typedef __attribute__((ext_vector_type(8))) short bf16x8;
typedef __attribute__((ext_vector_type(4))) float f32x4;

__device__ __forceinline__ u16 f2bf(float f) {
    union { u32 u; float f; } x; x.f = f;
    u32 u = x.u;
    u32 r = u + 0x7FFFu + ((u >> 16) & 1u);
    return (u16)(r >> 16);
}
__device__ __forceinline__ float blo(u32 b) {
    union { u32 u; float f; } x; x.u = b << 16; return x.f;
}
__device__ __forceinline__ float bhi(u32 b) {
    union { u32 u; float f; } x; x.u = b & 0xFFFF0000u; return x.f;
}

// ---------------------------------------------------------------------------
// 0) prep: Wt[n][k] = bf16(W[k][n]) via LDS tile (1 block) + bcur init.
// ---------------------------------------------------------------------------
__global__ __launch_bounds__(256) void prep_kernel(
    const float* __restrict__ W, u16* __restrict__ Wt, int* __restrict__ bcur)
{
    __shared__ u16 s[128 * 136];
    int t = threadIdx.x;
    bcur[t] = t * CAP;
    for (int i = 0; i < 64; ++i) {
        int idx = i * 256 + t;
        int k = idx >> 7, nn = idx & 127;
        s[nn * 136 + k] = f2bf(W[idx]);          // coalesced read
    }
    __syncthreads();
    for (int i = 0; i < 64; ++i) {
        int idx = i * 256 + t;
        int nn = idx >> 7, k = idx & 127;
        Wt[idx] = s[nn * 136 + k];               // coalesced write
    }
}

// ---------------------------------------------------------------------------
// 1) MFMA proj + fused scores. No input staging: A from X (inline cvt),
//    B from global Wt (L1-resident 32KB). LDS only for the C->Hb epilogue.
// ---------------------------------------------------------------------------
__global__ __launch_bounds__(256) void proj_kernel(
    const float* __restrict__ X, const u16* __restrict__ Wt,
    const float* __restrict__ AL, const float* __restrict__ AR,
    u32* __restrict__ Hb, float* __restrict__ Hs, float* __restrict__ Ht, int n)
{
    __shared__ alignas(16) float sH[64 * 132];   // 33.8 KB
    __shared__ float sAL[DIM], sAR[DIM];
    const int t = threadIdx.x;
    if (t < DIM) { sAL[t] = AL[t]; sAR[t] = AR[t]; }
    const int row0 = blockIdx.x * 64;
    const int w = t >> 6, lane = t & 63;
    const int quad = lane >> 4, nIdx = lane & 15;
    const int m = row0 + w * 16 + nIdx;

    f32x4 acc[8];
    #pragma unroll
    for (int c = 0; c < 8; ++c) acc[c] = (f32x4){0.f, 0.f, 0.f, 0.f};

    #pragma unroll
    for (int kq = 0; kq < 4; ++kq) {
        union { bf16x8 v; u16 e[8]; } a;
        if (m < n) {
            const float* xp = &X[(size_t)m * DIM + kq * 32 + quad * 8];
            float4 x0 = *(const float4*)xp;
            float4 x1 = *(const float4*)(xp + 4);
            a.e[0] = f2bf(x0.x); a.e[1] = f2bf(x0.y);
            a.e[2] = f2bf(x0.z); a.e[3] = f2bf(x0.w);
            a.e[4] = f2bf(x1.x); a.e[5] = f2bf(x1.y);
            a.e[6] = f2bf(x1.z); a.e[7] = f2bf(x1.w);
        } else {
            #pragma unroll
            for (int j = 0; j < 8; ++j) a.e[j] = 0;
        }
        #pragma unroll
        for (int c = 0; c < 8; ++c) {
            bf16x8 b = *(const bf16x8*)&Wt[(c * 16 + nIdx) * DIM + kq * 32 + quad * 8];
            acc[c] = __builtin_amdgcn_mfma_f32_16x16x32_bf16(a.v, b, acc[c], 0, 0, 0);
        }
    }
    #pragma unroll
    for (int c = 0; c < 8; ++c)
        #pragma unroll
        for (int r = 0; r < 4; ++r)
            sH[(w * 16 + quad * 4 + r) * 132 + c * 16 + nIdx] = acc[c][r];
    __syncthreads();

    // Hb: pack dim pairs -> bf16x2, coalesced
    #pragma unroll
    for (int i = 0; i < 16; ++i) {
        int idx = i * 256 + t;
        int r = idx >> 6, d2 = idx & 63;
        int gr = row0 + r;
        if (gr < n) {
            float2 hv = *(const float2*)&sH[r * 132 + 2 * d2];
            Hb[(size_t)gr * 64 + d2] = ((u32)f2bf(hv.y) << 16) | (u32)f2bf(hv.x);
        }
    }
    // scores: thread (row = t>>2, h = t&3)
    {
        int r = t >> 2, h = t & 3;
        float s = 0.f, s2 = 0.f;
        #pragma unroll
        for (int q = 0; q < ODIM; q += 4) {
            float4 hv = *(const float4*)&sH[r * 132 + h * ODIM + q];
            s  += hv.x*sAL[h*ODIM+q] + hv.y*sAL[h*ODIM+q+1] + hv.z*sAL[h*ODIM+q+2] + hv.w*sAL[h*ODIM+q+3];
            s2 += hv.x*sAR[h*ODIM+q] + hv.y*sAR[h*ODIM+q+1] + hv.z*sAR[h*ODIM+q+2] + hv.w*sAR[h*ODIM+q+3];
        }
        int gr = row0 + r;
        if (gr < n) { Hs[gr * HEADS + h] = s; Ht[gr * HEADS + h] = s2; }
    }
}

// ---------------------------------------------------------------------------
// shfl-based exclusive scan over 256 threads (3 barriers vs 16)
// ---------------------------------------------------------------------------
__device__ __forceinline__ int scan256_excl(int v, int t, int* wsum) {
    int lane = t & 63, w = t >> 6;
    int inc = v;
    #pragma unroll
    for (int ofs = 1; ofs < 64; ofs <<= 1) {
        int x = __shfl_up(inc, ofs);
        if (lane >= ofs) inc += x;
    }
    __syncthreads();                 // wsum safe to overwrite
    if (lane == 63) wsum[w] = inc;
    __syncthreads();
    int add = 0;
    #pragma unroll
    for (int j = 0; j < 4; ++j) add += (j < w) ? wsum[j] : 0;
    return inc - v + add;
}

// ---------------------------------------------------------------------------
// 2) LDS-staged partition into fixed per-bucket regions [b*CAP,(b+1)*CAP).
// ---------------------------------------------------------------------------
__global__ __launch_bounds__(256) void partition_kernel(
    const int* __restrict__ ei, int* __restrict__ bcur,
    u32* __restrict__ part, int E, int n)
{
    __shared__ u32 stage[PT];                  // 16 KB
    __shared__ u8  sbkt[PT];                   // 4 KB
    __shared__ int lcnt[256], loff[256], lcur[256], gbase[256];
    __shared__ int wsum[4];
    const int t = threadIdx.x;
    const int base = blockIdx.x * PT;
    lcnt[t] = 0;
    __syncthreads();

    u32 key[16];
    int bkt[16];
    #pragma unroll
    for (int i = 0; i < 16; ++i) {
        int e = base + i * 256 + t;
        bkt[i] = -1;
        key[i] = 0;
        if (e < E) {
            int src = ei[e];
            int tgt = ei[E + e];
            src = max(0, min(src, n - 1));
            tgt = max(0, min(tgt, n - 1));
            bkt[i] = src >> 8;
            key[i] = ((u32)(src & 255) << 17) | (u32)tgt;
            atomicAdd(&lcnt[bkt[i]], 1);
        }
    }
    __syncthreads();
    int cnt = lcnt[t];
    int ex = scan256_excl(cnt, t, wsum);
    loff[t] = ex;
    lcur[t] = ex;
    gbase[t] = (cnt > 0) ? atomicAdd(&bcur[t], cnt) : 0;
    __syncthreads();
    #pragma unroll
    for (int i = 0; i < 16; ++i) {
        if (bkt[i] >= 0) {
            int p = atomicAdd(&lcur[bkt[i]], 1);
            stage[p] = key[i];
            sbkt[p] = (u8)bkt[i];
        }
    }
    __syncthreads();
    int total = loff[255] + lcnt[255];
    for (int i = t; i < total; i += 256) {
        int b = sbkt[i];
        int dst = gbase[b] + (i - loff[b]);
        if (dst < (b + 1) * CAP) part[dst] = stage[i];   // overflow guard
    }
}

// ---------------------------------------------------------------------------
// 3) per-bucket counting sort -> off[] + csr_tgt. Each block derives its own
//    tpre/tsum by scanning bcur (scanB dispatch eliminated).
// ---------------------------------------------------------------------------
__global__ __launch_bounds__(256) void csrfill_kernel(
    const u32* __restrict__ part, const int* __restrict__ bcur,
    int* __restrict__ off, int* __restrict__ csr_tgt, int n, int ntiles)
{
    __shared__ int lc[256], lo[256], lcur[256];
    __shared__ int wsum[4];
    __shared__ int sBase, sCnt;
    const int b = blockIdx.x, t = threadIdx.x;
    // derive bucket counts from cursors; in-block exclusive scan
    int myc = (t < ntiles) ? (bcur[t] - t * CAP) : 0;
    myc = max(0, min(myc, CAP));
    int ex = scan256_excl(myc, t, wsum);
    if (t == b) { sBase = ex; sCnt = myc; }
    lc[t] = 0;
    __syncthreads();
    const int pbase = b * CAP;
    const int base = sBase, cnt = sCnt;
    for (int i = t; i < cnt; i += 256)
        atomicAdd(&lc[part[pbase + i] >> 17], 1);
    __syncthreads();
    int v = lc[t];
    int ex2 = scan256_excl(v, t, wsum);
    lo[t] = ex2;
    lcur[t] = ex2;
    __syncthreads();
    int node = b * 256 + t;
    if (node < n) off[node] = base + lo[t];
    if (b == ntiles - 1 && t == 0) off[n] = base + cnt;
    for (int i = t; i < cnt; i += 256) {
        u32 key = part[pbase + i];
        int p = atomicAdd(&lcur[key >> 17], 1);
        csr_tgt[base + p] = (int)(key & 0x1FFFFu);
    }
}

// ---------------------------------------------------------------------------
// 4) CSR-gather aggregation (unchanged): shfl w-dedup, 8x batches.
// ---------------------------------------------------------------------------
__global__ __launch_bounds__(256) void agg_kernel(
    const u32* __restrict__ Hb, const float* __restrict__ Hs,
    const float* __restrict__ Ht, const int* __restrict__ off,
    const int* __restrict__ csr_tgt, float2* __restrict__ out, int n, int E)
{
    int node = (blockIdx.x * 256 + threadIdx.x) >> 6;
    int L = threadIdx.x & 63;
    if (node >= n) return;
    int lo = off[node], hi = off[node + 1];
    lo = max(0, min(lo, E));
    hi = max(lo, min(hi, E));
    const int h = L >> 4;
    const int eSel = (L & 31) >> 2;
    const int hSel = L & 3;
    float4 hs4 = *(const float4*)&Hs[node * HEADS];
    float hsC = hSel == 0 ? hs4.x : hSel == 1 ? hs4.y : hSel == 2 ? hs4.z : hs4.w;
    float hsO = h == 0 ? hs4.x : h == 1 ? hs4.y : h == 2 ? hs4.z : hs4.w;
    float ax = 0.f, ay = 0.f, S = 0.f;

    int i = lo;
    for (; i + 8 <= hi; i += 8) {
        int tt[8];
        #pragma unroll
        for (int j = 0; j < 8; ++j) tt[j] = csr_tgt[i + j];
        int tsel = csr_tgt[i + eSel];
        float e = hsC + Ht[tsel * HEADS + hSel];
        float w = __expf(fminf(e > 0.f ? e : LRELU * e, 30.f));
        u32 bb[8];
        #pragma unroll
        for (int j = 0; j < 8; ++j) bb[j] = Hb[tt[j] * 64 + L];
        #pragma unroll
        for (int j = 0; j < 8; ++j) {
            float wj = __shfl(w, (j << 2) | h);
            ax += wj * blo(bb[j]);
            ay += wj * bhi(bb[j]);
            S += wj;
        }
    }
    for (; i < hi; ++i) {
        int tgt = csr_tgt[i];
        float e = hsO + Ht[tgt * HEADS + h];
        float w = __expf(fminf(e > 0.f ? e : LRELU * e, 30.f));
        u32 b = Hb[tgt * 64 + L];
        ax += w * blo(b);
        ay += w * bhi(b);
        S += w;
    }
    float inv = 1.f / (S + 1e-8f);
    float ox = ax * inv, oy = ay * inv;
    ox = ox > 0.f ? ox : (__expf(ox) - 1.f);
    oy = oy > 0.f ? oy : (__expf(oy) - 1.f);
    out[(size_t)node * 64 + L] = {ox, oy};
}

// ---------------------------------------------------------------------------
extern "C" void kernel_launch(void* const* d_in, const int* in_sizes, int n_in,
                              void* d_out, int out_size, void* d_ws, size_t ws_size,
                              hipStream_t stream) {
    const float* X  = (const float*)d_in[0];   // fp32
    const int*   EI = (const int*)d_in[1];     // int32[2E] block layout
    const float* W  = (const float*)d_in[2];   // fp32 row-major
    const float* AL = (const float*)d_in[3];
    const float* AR = (const float*)d_in[4];
    const int n = in_sizes[0] / DIM;      // 50000
    const int E = in_sizes[1] / 2;        // 1600000
    const int ntiles = (n + 255) / 256;   // 196 buckets

    char* ws = (char*)d_ws;
    size_t o = 0;
    auto alloc = [&](size_t bytes) -> void* {
        o = (o + 255) & ~(size_t)255;
        void* p = ws + o;
        o += bytes;
        return p;
    };
    int*   bcur    = (int*)alloc(256 * 4);
    u16*   Wt      = (u16*)alloc((size_t)DIM * DIM * 2);      // 32 KB
    int*   off     = (int*)alloc((size_t)(n + 1) * 4);
    float* Hs      = (float*)alloc((size_t)n * HEADS * 4);
    float* Ht      = (float*)alloc((size_t)n * HEADS * 4);
    int*   csr_tgt = (int*)alloc((size_t)E * 4);
    u32*   part    = (u32*)alloc((size_t)ntiles * CAP * 4);   // 7.2 MB
    u32*   Hb      = (u32*)alloc((size_t)n * 64 * 4);

    prep_kernel<<<1, 256, 0, stream>>>(W, Wt, bcur);
    proj_kernel<<<(n + 63) / 64, 256, 0, stream>>>(X, Wt, AL, AR, Hb, Hs, Ht, n);
    partition_kernel<<<(E + PT - 1) / PT, 256, 0, stream>>>(EI, bcur, part, E, n);
    csrfill_kernel<<<ntiles, 256, 0, stream>>>(part, bcur, off, csr_tgt, n, ntiles);
    agg_kernel<<<(n + 3) / 4, 256, 0, stream>>>(
        Hb, Hs, Ht, off, csr_tgt, (float2*)d_out, n, E);
}

// Round 20
// 206.797 us; speedup vs baseline: 7.3112x; 1.0074x over previous
//
#include <hip/hip_runtime.h>

#define DIM 128
#define HEADS 4
#define ODIM 32
#define LRELU 0.2f
#define PT 4096
#define CAP 9216

typedef unsigned int u32;
typedef unsigned short u16;
typedef unsigned char u8;

typedef __attribute__((ext_vector_type(8))) short bf16x8;
typedef __attribute__((ext_vector_type(4))) float f32x4;

__device__ __forceinline__ u16 f2bf(float f) {
    union { u32 u; float f; } x; x.f = f;
    u32 u = x.u;
    u32 r = u + 0x7FFFu + ((u >> 16) & 1u);
    return (u16)(r >> 16);
}
__device__ __forceinline__ float blo(u32 b) {
    union { u32 u; float f; } x; x.u = b << 16; return x.f;
}
__device__ __forceinline__ float bhi(u32 b) {
    union { u32 u; float f; } x; x.u = b & 0xFFFF0000u; return x.f;
}

// ---------------------------------------------------------------------------
// 0) prep: Wt[n][k] = bf16(W[k][n]) via LDS tile (1 block) + bcur init.
// ---------------------------------------------------------------------------
__global__ __launch_bounds__(256) void prep_kernel(
    const float* __restrict__ W, u16* __restrict__ Wt, int* __restrict__ bcur)
{
    __shared__ u16 s[128 * 136];
    int t = threadIdx.x;
    bcur[t] = t * CAP;
    for (int i = 0; i < 64; ++i) {
        int idx = i * 256 + t;
        int k = idx >> 7, nn = idx & 127;
        s[nn * 136 + k] = f2bf(W[idx]);          // coalesced read
    }
    __syncthreads();
    for (int i = 0; i < 64; ++i) {
        int idx = i * 256 + t;
        int nn = idx >> 7, k = idx & 127;
        Wt[idx] = s[nn * 136 + k];               // coalesced write
    }
}

// ---------------------------------------------------------------------------
// 1) MFMA proj + fused scores. A from X (inline cvt), B from global Wt.
// ---------------------------------------------------------------------------
__global__ __launch_bounds__(256) void proj_kernel(
    const float* __restrict__ X, const u16* __restrict__ Wt,
    const float* __restrict__ AL, const float* __restrict__ AR,
    u32* __restrict__ Hb, float* __restrict__ Hs, float* __restrict__ Ht, int n)
{
    __shared__ alignas(16) float sH[64 * 132];   // 33.8 KB
    __shared__ float sAL[DIM], sAR[DIM];
    const int t = threadIdx.x;
    if (t < DIM) { sAL[t] = AL[t]; sAR[t] = AR[t]; }
    const int row0 = blockIdx.x * 64;
    const int w = t >> 6, lane = t & 63;
    const int quad = lane >> 4, nIdx = lane & 15;
    const int m = row0 + w * 16 + nIdx;

    f32x4 acc[8];
    #pragma unroll
    for (int c = 0; c < 8; ++c) acc[c] = (f32x4){0.f, 0.f, 0.f, 0.f};

    #pragma unroll
    for (int kq = 0; kq < 4; ++kq) {
        union { bf16x8 v; u16 e[8]; } a;
        if (m < n) {
            const float* xp = &X[(size_t)m * DIM + kq * 32 + quad * 8];
            float4 x0 = *(const float4*)xp;
            float4 x1 = *(const float4*)(xp + 4);
            a.e[0] = f2bf(x0.x); a.e[1] = f2bf(x0.y);
            a.e[2] = f2bf(x0.z); a.e[3] = f2bf(x0.w);
            a.e[4] = f2bf(x1.x); a.e[5] = f2bf(x1.y);
            a.e[6] = f2bf(x1.z); a.e[7] = f2bf(x1.w);
        } else {
            #pragma unroll
            for (int j = 0; j < 8; ++j) a.e[j] = 0;
        }
        #pragma unroll
        for (int c = 0; c < 8; ++c) {
            bf16x8 b = *(const bf16x8*)&Wt[(c * 16 + nIdx) * DIM + kq * 32 + quad * 8];
            acc[c] = __builtin_amdgcn_mfma_f32_16x16x32_bf16(a.v, b, acc[c], 0, 0, 0);
        }
    }
    #pragma unroll
    for (int c = 0; c < 8; ++c)
        #pragma unroll
        for (int r = 0; r < 4; ++r)
            sH[(w * 16 + quad * 4 + r) * 132 + c * 16 + nIdx] = acc[c][r];
    __syncthreads();

    #pragma unroll
    for (int i = 0; i < 16; ++i) {
        int idx = i * 256 + t;
        int r = idx >> 6, d2 = idx & 63;
        int gr = row0 + r;
        if (gr < n) {
            float2 hv = *(const float2*)&sH[r * 132 + 2 * d2];
            Hb[(size_t)gr * 64 + d2] = ((u32)f2bf(hv.y) << 16) | (u32)f2bf(hv.x);
        }
    }
    {
        int r = t >> 2, h = t & 3;
        float s = 0.f, s2 = 0.f;
        #pragma unroll
        for (int q = 0; q < ODIM; q += 4) {
            float4 hv = *(const float4*)&sH[r * 132 + h * ODIM + q];
            s  += hv.x*sAL[h*ODIM+q] + hv.y*sAL[h*ODIM+q+1] + hv.z*sAL[h*ODIM+q+2] + hv.w*sAL[h*ODIM+q+3];
            s2 += hv.x*sAR[h*ODIM+q] + hv.y*sAR[h*ODIM+q+1] + hv.z*sAR[h*ODIM+q+2] + hv.w*sAR[h*ODIM+q+3];
        }
        int gr = row0 + r;
        if (gr < n) { Hs[gr * HEADS + h] = s; Ht[gr * HEADS + h] = s2; }
    }
}

// ---------------------------------------------------------------------------
// shfl-based exclusive scan over 256 threads
// ---------------------------------------------------------------------------
__device__ __forceinline__ int scan256_excl(int v, int t, int* wsum) {
    int lane = t & 63, w = t >> 6;
    int inc = v;
    #pragma unroll
    for (int ofs = 1; ofs < 64; ofs <<= 1) {
        int x = __shfl_up(inc, ofs);
        if (lane >= ofs) inc += x;
    }
    __syncthreads();
    if (lane == 63) wsum[w] = inc;
    __syncthreads();
    int add = 0;
    #pragma unroll
    for (int j = 0; j < 4; ++j) add += (j < w) ? wsum[j] : 0;
    return inc - v + add;
}

// ---------------------------------------------------------------------------
// 2) LDS-staged partition, 4-way privatized hists/cursors (contention /4).
//    Fixed per-bucket regions [b*CAP,(b+1)*CAP). bucket = src>>8.
// ---------------------------------------------------------------------------
__global__ __launch_bounds__(256) void partition_kernel(
    const int* __restrict__ ei, int* __restrict__ bcur,
    u32* __restrict__ part, int E, int n)
{
    __shared__ u32 stage[PT];                  // 16 KB
    __shared__ u8  sbkt[PT];                   // 4 KB
    __shared__ int lcnt4[4][256];              // 4 KB (per-wave hists)
    __shared__ int lcur4[4][256];              // 4 KB (per-wave cursors)
    __shared__ int loff[256], ltot[256], gbase[256];
    __shared__ int wsum[4];
    const int t = threadIdx.x;
    const int wv = t >> 6;
    const int base = blockIdx.x * PT;
    lcnt4[0][t] = 0; lcnt4[1][t] = 0; lcnt4[2][t] = 0; lcnt4[3][t] = 0;
    __syncthreads();

    u32 key[16];
    int bkt[16];
    #pragma unroll
    for (int i = 0; i < 16; ++i) {
        int e = base + i * 256 + t;
        bkt[i] = -1;
        key[i] = 0;
        if (e < E) {
            int src = ei[e];
            int tgt = ei[E + e];
            src = max(0, min(src, n - 1));
            tgt = max(0, min(tgt, n - 1));
            bkt[i] = src >> 8;
            key[i] = ((u32)(src & 255) << 17) | (u32)tgt;
            atomicAdd(&lcnt4[wv][bkt[i]], 1);
        }
    }
    __syncthreads();
    int c0 = lcnt4[0][t], c1 = lcnt4[1][t], c2 = lcnt4[2][t], c3 = lcnt4[3][t];
    int total = c0 + c1 + c2 + c3;
    int ex = scan256_excl(total, t, wsum);
    loff[t] = ex;
    ltot[t] = total;
    lcur4[0][t] = ex;
    lcur4[1][t] = ex + c0;
    lcur4[2][t] = ex + c0 + c1;
    lcur4[3][t] = ex + c0 + c1 + c2;
    gbase[t] = (total > 0) ? atomicAdd(&bcur[t], total) : 0;
    __syncthreads();
    #pragma unroll
    for (int i = 0; i < 16; ++i) {
        if (bkt[i] >= 0) {
            int p = atomicAdd(&lcur4[wv][bkt[i]], 1);
            stage[p] = key[i];
            sbkt[p] = (u8)bkt[i];
        }
    }
    __syncthreads();
    int tot = loff[255] + ltot[255];
    for (int i = t; i < tot; i += 256) {
        int b = sbkt[i];
        int dst = gbase[b] + (i - loff[b]);
        if (dst < (b + 1) * CAP) part[dst] = stage[i];   // overflow guard
    }
}

// ---------------------------------------------------------------------------
// 3) per-bucket counting sort, 4-way privatized -> off[] + csr_tgt.
// ---------------------------------------------------------------------------
__global__ __launch_bounds__(256) void csrfill_kernel(
    const u32* __restrict__ part, const int* __restrict__ bcur,
    int* __restrict__ off, int* __restrict__ csr_tgt, int n, int ntiles)
{
    __shared__ int lc4[4][256];                // 4 KB
    __shared__ int lcur4[4][256];              // 4 KB
    __shared__ int lo[256];
    __shared__ int wsum[4];
    __shared__ int sBase, sCnt;
    const int b = blockIdx.x, t = threadIdx.x;
    const int wv = t >> 6;
    // derive bucket base/cnt from cursors
    int myc = (t < ntiles) ? (bcur[t] - t * CAP) : 0;
    myc = max(0, min(myc, CAP));
    int ex = scan256_excl(myc, t, wsum);
    if (t == b) { sBase = ex; sCnt = myc; }
    lc4[0][t] = 0; lc4[1][t] = 0; lc4[2][t] = 0; lc4[3][t] = 0;
    __syncthreads();
    const int pbase = b * CAP;
    const int base = sBase, cnt = sCnt;
    for (int i = t; i < cnt; i += 256)
        atomicAdd(&lc4[wv][part[pbase + i] >> 17], 1);
    __syncthreads();
    int c0 = lc4[0][t], c1 = lc4[1][t], c2 = lc4[2][t], c3 = lc4[3][t];
    int total = c0 + c1 + c2 + c3;
    int ex2 = scan256_excl(total, t, wsum);
    lo[t] = ex2;
    lcur4[0][t] = ex2;
    lcur4[1][t] = ex2 + c0;
    lcur4[2][t] = ex2 + c0 + c1;
    lcur4[3][t] = ex2 + c0 + c1 + c2;
    __syncthreads();
    int node = b * 256 + t;
    if (node < n) off[node] = base + lo[t];
    if (b == ntiles - 1 && t == 0) off[n] = base + cnt;
    for (int i = t; i < cnt; i += 256) {
        u32 key = part[pbase + i];
        int p = atomicAdd(&lcur4[wv][key >> 17], 1);
        csr_tgt[base + p] = (int)(key & 0x1FFFFu);
    }
}

// ---------------------------------------------------------------------------
// 4) CSR-gather aggregation: shfl w-dedup, 8x batches, duty-lane S partials.
// ---------------------------------------------------------------------------
__global__ __launch_bounds__(256) void agg_kernel(
    const u32* __restrict__ Hb, const float* __restrict__ Hs,
    const float* __restrict__ Ht, const int* __restrict__ off,
    const int* __restrict__ csr_tgt, float2* __restrict__ out, int n, int E)
{
    int node = (blockIdx.x * 256 + threadIdx.x) >> 6;
    int L = threadIdx.x & 63;
    if (node >= n) return;
    int lo = off[node], hi = off[node + 1];
    lo = max(0, min(lo, E));
    hi = max(lo, min(hi, E));
    const int h = L >> 4;
    const int eSel = (L & 31) >> 2;
    const int hSel = L & 3;
    float4 hs4 = *(const float4*)&Hs[node * HEADS];
    float hsC = hSel == 0 ? hs4.x : hSel == 1 ? hs4.y : hSel == 2 ? hs4.z : hs4.w;
    float hsO = h == 0 ? hs4.x : h == 1 ? hs4.y : h == 2 ? hs4.z : hs4.w;
    float ax = 0.f, ay = 0.f, Sd = 0.f, Srem = 0.f;

    int i = lo;
    for (; i + 8 <= hi; i += 8) {
        int tt[8];
        #pragma unroll
        for (int j = 0; j < 8; ++j) tt[j] = csr_tgt[i + j];
        int tsel = csr_tgt[i + eSel];
        float e = hsC + Ht[tsel * HEADS + hSel];
        float w = __expf(fminf(e > 0.f ? e : LRELU * e, 30.f));
        Sd += w;                              // duty partial (lanes mirror mod 32)
        u32 bb[8];
        #pragma unroll
        for (int j = 0; j < 8; ++j) bb[j] = Hb[tt[j] * 64 + L];
        #pragma unroll
        for (int j = 0; j < 8; ++j) {
            float wj = __shfl(w, (j << 2) | h);
            ax += wj * blo(bb[j]);
            ay += wj * bhi(bb[j]);
        }
    }
    for (; i < hi; ++i) {
        int tgt = csr_tgt[i];
        float e = hsO + Ht[tgt * HEADS + h];
        float w = __expf(fminf(e > 0.f ? e : LRELU * e, 30.f));
        u32 b = Hb[tgt * 64 + L];
        ax += w * blo(b);
        ay += w * bhi(b);
        Srem += w;
    }
    float S = Srem;
    #pragma unroll
    for (int j = 0; j < 8; ++j) S += __shfl(Sd, (j << 2) | h);
    float inv = 1.f / (S + 1e-8f);
    float ox = ax * inv, oy = ay * inv;
    ox = ox > 0.f ? ox : (__expf(ox) - 1.f);
    oy = oy > 0.f ? oy : (__expf(oy) - 1.f);
    out[(size_t)node * 64 + L] = {ox, oy};
}

// ---------------------------------------------------------------------------
extern "C" void kernel_launch(void* const* d_in, const int* in_sizes, int n_in,
                              void* d_out, int out_size, void* d_ws, size_t ws_size,
                              hipStream_t stream) {
    const float* X  = (const float*)d_in[0];   // fp32
    const int*   EI = (const int*)d_in[1];     // int32[2E] block layout
    const float* W  = (const float*)d_in[2];   // fp32 row-major
    const float* AL = (const float*)d_in[3];
    const float* AR = (const float*)d_in[4];
    const int n = in_sizes[0] / DIM;      // 50000
    const int E = in_sizes[1] / 2;        // 1600000
    const int ntiles = (n + 255) / 256;   // 196 buckets

    char* ws = (char*)d_ws;
    size_t o = 0;
    auto alloc = [&](size_t bytes) -> void* {
        o = (o + 255) & ~(size_t)255;
        void* p = ws + o;
        o += bytes;
        return p;
    };
    int*   bcur    = (int*)alloc(256 * 4);
    u16*   Wt      = (u16*)alloc((size_t)DIM * DIM * 2);      // 32 KB
    int*   off     = (int*)alloc((size_t)(n + 1) * 4);
    float* Hs      = (float*)alloc((size_t)n * HEADS * 4);
    float* Ht      = (float*)alloc((size_t)n * HEADS * 4);
    int*   csr_tgt = (int*)alloc((size_t)E * 4);
    u32*   part    = (u32*)alloc((size_t)ntiles * CAP * 4);   // 7.2 MB
    u32*   Hb      = (u32*)alloc((size_t)n * 64 * 4);

    prep_kernel<<<1, 256, 0, stream>>>(W, Wt, bcur);
    proj_kernel<<<(n + 63) / 64, 256, 0, stream>>>(X, Wt, AL, AR, Hb, Hs, Ht, n);
    partition_kernel<<<(E + PT - 1) / PT, 256, 0, stream>>>(EI, bcur, part, E, n);
    csrfill_kernel<<<ntiles, 256, 0, stream>>>(part, bcur, off, csr_tgt, n, ntiles);
    agg_kernel<<<(n + 3) / 4, 256, 0, stream>>>(
        Hb, Hs, Ht, off, csr_tgt, (float2*)d_out, n, E);
}